// Round 6
// baseline (813.439 us; speedup 1.0000x reference)
//
#include <hip/hip_runtime.h>
#include <hip/hip_bf16.h>
#include <cstdio>

#define LQ 2048      // L
#define BB 2         // batch
#define BL 4096      // B*L rows
#define DMODEL 2048
#define DIN 4096
#define NH 64
#define HD 64
#define NST 128
#define CONVD 4352
#define PROJD 8512
#define PROJ_PAD2 8704   // pad to 256 multiple
#define PXW 4416     // projx width: CONVD + NH
#define CHK 256
#define NCH 8        // chunks per batch

typedef __attribute__((ext_vector_type(8))) short short8;
typedef __attribute__((ext_vector_type(4))) float f32x4;

__device__ __forceinline__ unsigned short f2bu(float x) {
  __hip_bfloat16 h = __float2bfloat16(x);
  return __builtin_bit_cast(unsigned short, h);
}

__device__ __forceinline__ f32x4 mfma16(short8 a, short8 b, f32x4 c) {
  return __builtin_amdgcn_mfma_f32_16x16x32_bf16(a, b, c, 0, 0, 0);
}

#define GLD16(gptr, lptr)                                                  \
  __builtin_amdgcn_global_load_lds(                                        \
      (const __attribute__((address_space(1))) void*)(gptr),               \
      (__attribute__((address_space(3))) void*)(lptr), 16, 0, 0)

// ---------------- cast fp32 -> bf16 (with zero tail padding) ----------------
__global__ void k_cast_pad(const float* __restrict__ in, unsigned short* __restrict__ out,
                           long n, long ntot) {
  long i = (long)blockIdx.x * blockDim.x + threadIdx.x;
  long stride = (long)gridDim.x * blockDim.x;
  for (; i < ntot; i += stride)
    out[i] = (i < n) ? f2bu(in[i]) : (unsigned short)0;
}

// swizzled fragment read from a [R][64] bf16 LDS tile (involution: cg ^= row&7)
__device__ __forceinline__ short8 rdfrag(const unsigned short (*mp)[64], int rowbase,
                                         int lane, int kh) {
  const int row = rowbase + (lane & 15);
  const int cg = (((kh << 2) + (lane >> 4)) ^ (lane & 7)) << 3;
  return *reinterpret_cast<const short8*>(&mp[row][cg]);
}

// ==== 256x128 pipelined GEMM: C(M,Nreal) = A(M,K) @ B(Npad,K)^T ============
// 512 thr = 8 waves (4m x 2n), per-wave 64x64 output. BK=64.
// 3-deep LDS pipeline (144 KiB): stage tile t+2 during tile t; entry wait
// vmcnt(6) with 12 in flight (vmcnt(0) only on final tile). 6 staging rounds
// per tile [A0,A1,A2,A3,B0,B1], 3 issued per phase. T2 swizzle + T5 setprio.
// SPLIT=true: cols [0,DIN) -> bf16 gateb; cols [DIN,PROJD) -> fp32 projx.
template <bool SPLIT>
__global__ __launch_bounds__(512) void k_gemm256x128(
    const unsigned short* __restrict__ A, const unsigned short* __restrict__ Bw,
    float* __restrict__ C, unsigned short* __restrict__ gateb,
    float* __restrict__ projx, int Nreal, int K) {
  __shared__ unsigned short shA[3][256][64];
  __shared__ unsigned short shB[3][128][64];
  const int tid = threadIdx.x;
  const int lane = tid & 63, w = tid >> 6;
  const int wm = w >> 1, wn = w & 1;
  const int gx = gridDim.x;  // N tiles (128-wide)
  const int nwg = gx * gridDim.y;
  const int bid = blockIdx.y * gx + blockIdx.x;
  const int qq = nwg >> 3;   // nwg % 8 == 0 at both call sites
  const int swz = (bid & 7) * qq + (bid >> 3);
  const int m0 = (swz / gx) * 256, n0 = (swz % gx) * 128;
  const int srow = tid >> 3;
  const int sdst = (tid & 7) * 8;                       // linear LDS col
  const int ssrc = ((tid & 7) ^ ((tid >> 3) & 7)) * 8;  // swizzled gmem col
  const unsigned short* Ab = A + (size_t)m0 * K;
  const unsigned short* Bb = Bw + (size_t)n0 * K;
  const int nt = K >> 6;

#define STA(bf, r0, kk) \
  GLD16(Ab + (size_t)((r0) + srow) * K + (kk) + ssrc, &shA[bf][(r0) + srow][sdst])
#define STB(bf, r0, kk) \
  GLD16(Bb + (size_t)((r0) + srow) * K + (kk) + ssrc, &shB[bf][(r0) + srow][sdst])

#define MFMA_HALF(kh)                                                      \
  {                                                                        \
    short8 af[4], bg[4];                                                   \
    _Pragma("unroll") for (int i = 0; i < 4; i++)                          \
        af[i] = rdfrag(shA[cur], wm * 64 + i * 16, lane, kh);              \
    _Pragma("unroll") for (int j = 0; j < 4; j++)                          \
        bg[j] = rdfrag(shB[cur], wn * 64 + j * 16, lane, kh);              \
    __builtin_amdgcn_s_setprio(1);                                         \
    _Pragma("unroll") for (int i = 0; i < 4; i++)                          \
        _Pragma("unroll") for (int j = 0; j < 4; j++)                      \
            acc[i][j] = mfma16(af[i], bg[j], acc[i][j]);                   \
    __builtin_amdgcn_s_setprio(0);                                         \
  }

  f32x4 acc[4][4] = {};
  // prologue: stage tiles 0 and 1 (12 loads outstanding)
  STA(0, 0, 0); STA(0, 64, 0); STA(0, 128, 0); STA(0, 192, 0);
  STB(0, 0, 0); STB(0, 64, 0);
  STA(1, 0, 64); STA(1, 64, 64); STA(1, 128, 64); STA(1, 192, 64);
  STB(1, 0, 64); STB(1, 64, 64);

  for (int t = 0; t < nt; ++t) {
    const int cur = t % 3;
    const bool more = (t + 2 < nt);
    const int nx2 = more ? (t + 2) % 3 : 0;
    const int kb2 = (t + 2) << 6;
    // entry: tile t's 6 rounds must have landed (globally, via barrier)
    if (t + 1 < nt) asm volatile("s_waitcnt vmcnt(6)" ::: "memory");
    else            asm volatile("s_waitcnt vmcnt(0)" ::: "memory");
    __builtin_amdgcn_s_barrier();
    // ---- phase 0: stage A0-A2 of t+2; compute k-half 0
    if (more) { STA(nx2, 0, kb2); STA(nx2, 64, kb2); STA(nx2, 128, kb2); }
    MFMA_HALF(0)
    __builtin_amdgcn_s_barrier();
    // ---- phase 1: stage A3,B0,B1 of t+2; compute k-half 1
    if (more) { STA(nx2, 192, kb2); STB(nx2, 0, kb2); STB(nx2, 64, kb2); }
    MFMA_HALF(1)
    // no trailing barrier: next tile's entry vmcnt+barrier covers reuse
  }
#undef MFMA_HALF
#undef STA
#undef STB

  // epilogue
#pragma unroll
  for (int i = 0; i < 4; i++) {
    const int row = m0 + wm * 64 + i * 16 + ((lane >> 4) << 2);
#pragma unroll
    for (int j = 0; j < 4; j++) {
      const int col = n0 + wn * 64 + j * 16 + (lane & 15);
      if (SPLIT) {
        if (col < DIN) {
#pragma unroll
          for (int v = 0; v < 4; v++)
            gateb[(size_t)(row + v) * DIN + col] = f2bu(acc[i][j][v]);
        } else if (col < PROJD) {
#pragma unroll
          for (int v = 0; v < 4; v++)
            projx[(size_t)(row + v) * PXW + (col - DIN)] = acc[i][j][v];
        }
      } else {
        if (col < Nreal) {
#pragma unroll
          for (int v = 0; v < 4; v++)
            C[(size_t)(row + v) * Nreal + col] = acc[i][j][v];
        }
      }
    }
  }
}

// ---------------- causal depthwise conv (K=4) + SiLU ------------------------
__global__ __launch_bounds__(256) void k_conv_silu(
    const float* __restrict__ projx, const float* __restrict__ cw,
    const float* __restrict__ cb, float* __restrict__ xbc) {
  const int ch = blockIdx.x * 256 + threadIdx.x;  // 17*256 = 4352 exact
  const int bt = blockIdx.y;
  const int b = bt >> 11, t = bt & 2047;
  float acc = cb[ch];
#pragma unroll
  for (int i = 0; i < 4; i++) {
    int tt = t - 3 + i;
    if (tt >= 0)
      acc += cw[ch * 4 + i] * projx[((size_t)b * LQ + tt) * PXW + ch];
  }
  float o = acc / (1.f + __expf(-acc));
  xbc[(size_t)bt * CONVD + ch] = o;
}

// ------- dt softplus + per-chunk cumsum(dt*A): parallel 2-phase scan --------
__global__ __launch_bounds__(256) void k_dt(
    const float* __restrict__ projx, const float* __restrict__ dtb,
    const float* __restrict__ alog, float* __restrict__ dtv,
    float* __restrict__ dac) {
  const int bc = blockIdx.x;  // 16 = b*8+c
  const int b = bc >> 3, c = bc & 7;
  const int h = threadIdx.x & 63, q = threadIdx.x >> 6;
  const float bias = dtb[h];
  const float Ah = -__expf(alog[h]);
  const size_t base = (size_t)b * LQ + c * CHK + q * 64;
  float vals[64];
  float part = 0.f;
#pragma unroll
  for (int j = 0; j < 64; j++) {
    float raw = projx[(base + j) * PXW + CONVD + h] + bias;
    float dt = raw > 20.f ? raw : log1pf(__expf(raw));
    vals[j] = dt;
    dtv[(base + j) * NH + h] = dt;
    part += dt;
  }
  __shared__ float partials[4][64];
  partials[q][h] = part;
  __syncthreads();
  float cum = 0.f;
  for (int qq = 0; qq < q; qq++) cum += partials[qq][h];
  cum *= Ah;
#pragma unroll
  for (int j = 0; j < 64; j++) {
    cum += vals[j] * Ah;
    dac[(base + j) * NH + h] = cum;
  }
}

// ---------------- CB[t][s] = sum_n C[t][n]*B[s][n] per (b,c) ----------------
__global__ __launch_bounds__(256) void k_cb(const float* __restrict__ xbc,
                                            float* __restrict__ cbuf) {
  const int q = blockIdx.x;   // 4 quadrants
  const int bc = blockIdx.y;  // 16
  const int b = bc >> 3, c = bc & 7;
  const int qt = q >> 1, qs = q & 1;
  __shared__ unsigned short lC[128][136];
  __shared__ unsigned short lB[128][136];
  const int tid = threadIdx.x, lane = tid & 63, w = tid >> 6;
  {
    int r = tid >> 1, hf = tid & 1;
    size_t rowc = (size_t)b * LQ + c * CHK + qt * 128 + r;
    const float* crp = xbc + rowc * CONVD + DIN + NST + hf * 64;
    size_t rowb = (size_t)b * LQ + c * CHK + qs * 128 + r;
    const float* brp = xbc + rowb * CONVD + DIN + hf * 64;
#pragma unroll
    for (int n = 0; n < 64; n++) {
      lC[r][hf * 64 + n] = f2bu(crp[n]);
      lB[r][hf * 64 + n] = f2bu(brp[n]);
    }
  }
  __syncthreads();
  const int wr = (w >> 1) * 64, wc = (w & 1) * 64;
  f32x4 acc[4][4] = {};
#pragma unroll
  for (int kk = 0; kk < 128; kk += 32) {
    short8 a[4], bb[4];
    const int ko = kk + ((lane >> 4) << 3);
#pragma unroll
    for (int i = 0; i < 4; i++) {
      a[i] = *reinterpret_cast<const short8*>(&lC[wr + i * 16 + (lane & 15)][ko]);
      bb[i] = *reinterpret_cast<const short8*>(&lB[wc + i * 16 + (lane & 15)][ko]);
    }
#pragma unroll
    for (int mi = 0; mi < 4; mi++)
#pragma unroll
      for (int ni = 0; ni < 4; ni++)
        acc[mi][ni] = mfma16(a[mi], bb[ni], acc[mi][ni]);
  }
  float* outp = cbuf + (size_t)bc * (CHK * CHK);
#pragma unroll
  for (int mi = 0; mi < 4; mi++) {
    const int t = qt * 128 + wr + mi * 16 + ((lane >> 4) << 2);
#pragma unroll
    for (int ni = 0; ni < 4; ni++) {
      const int s = qs * 128 + wc + ni * 16 + (lane & 15);
#pragma unroll
      for (int v = 0; v < 4; v++)
        outp[(size_t)(t + v) * CHK + s] = acc[mi][ni][v];
    }
  }
}

// ---------------- fused Y_diag + states per (b,c,h) -------------------------
__global__ __launch_bounds__(256) void k_diag(
    const float* __restrict__ xbc, const float* __restrict__ dtv,
    const float* __restrict__ dac, const float* __restrict__ cbuf,
    float* __restrict__ y, float* __restrict__ st) {
  const int h = blockIdx.x, c = blockIdx.y, b = blockIdx.z;
  const int cs = c * CHK;
  __shared__ unsigned short lXt[64][264];   // (p, s) x*dt, bf16
  __shared__ unsigned short lBt[128][264];  // (n, s) B*decay, bf16
  __shared__ unsigned short lS[256][40];    // (t, s-block32) masked S, bf16
  __shared__ float lda[256];
  const int tid = threadIdx.x, lane = tid & 63, w = tid >> 6;
  lda[tid] = dac[((size_t)b * LQ + cs + tid) * NH + h];
  __syncthreads();
  const float dalast = lda[255];
  {
    const int s = tid;
    const float* xrow = xbc + ((size_t)b * LQ + cs + s) * CONVD;
    const float dts = dtv[((size_t)b * LQ + cs + s) * NH + h];
    const f32x4* x4 = reinterpret_cast<const f32x4*>(xrow + h * HD);
#pragma unroll
    for (int p4 = 0; p4 < 16; p4++) {
      f32x4 v = x4[p4];
#pragma unroll
      for (int u = 0; u < 4; u++) lXt[p4 * 4 + u][s] = f2bu(v[u] * dts);
    }
    const float dec = __expf(dalast - lda[s]);
    const f32x4* b4 = reinterpret_cast<const f32x4*>(xrow + DIN);
#pragma unroll
    for (int n4 = 0; n4 < 32; n4++) {
      f32x4 v = b4[n4];
#pragma unroll
      for (int u = 0; u < 4; u++) lBt[n4 * 4 + u][s] = f2bu(v[u] * dec);
    }
  }
  __syncthreads();
  const float* cbp = cbuf + ((size_t)(b * NCH + c)) * (CHK * CHK);
  const float da_t = lda[tid];
  f32x4 accY[4][4] = {};
  f32x4 accS[4][2] = {};
  const int wn = w * 32;
  for (int sb = 0; sb < 8; sb++) {
    {
      const int t = tid;
      const f32x4* cr = reinterpret_cast<const f32x4*>(cbp + (size_t)t * CHK + sb * 32);
      f32x4 vv[8];
#pragma unroll
      for (int j4 = 0; j4 < 8; j4++) vv[j4] = cr[j4];
#pragma unroll
      for (int g = 0; g < 4; g++) {
        short8 pk;
#pragma unroll
        for (int e = 0; e < 8; e++) {
          const int j = g * 8 + e;
          const int s = sb * 32 + j;
          const float x = vv[j >> 2][j & 3];
          const float val = (s <= t) ? x * __expf(da_t - lda[s]) : 0.f;
          pk[e] = (short)f2bu(val);
        }
        *reinterpret_cast<short8*>(&lS[t][g * 8]) = pk;
      }
    }
    __syncthreads();
    short8 sf[4], xf[4], btf[2];
    const int ko = ((lane >> 4) << 3);
#pragma unroll
    for (int i = 0; i < 4; i++) {
      sf[i] = *reinterpret_cast<const short8*>(&lS[w * 64 + i * 16 + (lane & 15)][ko]);
      xf[i] = *reinterpret_cast<const short8*>(&lXt[i * 16 + (lane & 15)][sb * 32 + ko]);
    }
#pragma unroll
    for (int i = 0; i < 2; i++)
      btf[i] = *reinterpret_cast<const short8*>(&lBt[wn + i * 16 + (lane & 15)][sb * 32 + ko]);
#pragma unroll
    for (int mi = 0; mi < 4; mi++)
#pragma unroll
      for (int ni = 0; ni < 4; ni++)
        accY[mi][ni] = mfma16(sf[mi], xf[ni], accY[mi][ni]);
#pragma unroll
    for (int mi = 0; mi < 4; mi++)
#pragma unroll
      for (int nj = 0; nj < 2; nj++)
        accS[mi][nj] = mfma16(xf[mi], btf[nj], accS[mi][nj]);
    __syncthreads();
  }
#pragma unroll
  for (int mi = 0; mi < 4; mi++) {
    const int t = w * 64 + mi * 16 + ((lane >> 4) << 2);
#pragma unroll
    for (int ni = 0; ni < 4; ni++) {
      const int p = ni * 16 + (lane & 15);
#pragma unroll
      for (int v = 0; v < 4; v++)
        y[((size_t)b * LQ + cs + t + v) * DIN + h * HD + p] = accY[mi][ni][v];
    }
  }
  float* stp = st + ((size_t)((b * NCH + c) * NH + h)) * (HD * NST);
#pragma unroll
  for (int mi = 0; mi < 4; mi++) {
    const int p = mi * 16 + ((lane >> 4) << 2);
#pragma unroll
    for (int nj = 0; nj < 2; nj++) {
      const int n = wn + nj * 16 + (lane & 15);
#pragma unroll
      for (int v = 0; v < 4; v++)
        stp[(size_t)(p + v) * NST + n] = accS[mi][nj][v];
    }
  }
}

// ---------------- inter-chunk state scan ------------------------------------
__global__ void k_scan(const float* __restrict__ st, const float* __restrict__ dac,
                       float* __restrict__ pv) {
  const int h = blockIdx.x, b = blockIdx.y;
  const int tid = threadIdx.x;
  float P[32];
#pragma unroll
  for (int j = 0; j < 32; j++) P[j] = 0.f;
  for (int c = 0; c < NCH; c++) {
    const size_t base = ((size_t)((b * NCH + c) * NH + h)) * (HD * NST);
#pragma unroll
    for (int j = 0; j < 32; j++) pv[base + tid + 256 * j] = P[j];
    const float d = __expf(dac[((size_t)b * LQ + c * CHK + 255) * NH + h]);
#pragma unroll
    for (int j = 0; j < 32; j++) P[j] = P[j] * d + st[base + tid + 256 * j];
  }
}

// ---------------- Y_off + D*x accumulate into y -----------------------------
__global__ __launch_bounds__(256) void k_off(
    const float* __restrict__ xbc, const float* __restrict__ dac,
    const float* __restrict__ pv, const float* __restrict__ Dp,
    float* __restrict__ y) {
  const int h = blockIdx.x, c = blockIdx.y, b = blockIdx.z;
  const int cs = c * CHK;
  __shared__ unsigned short lC[256][136];  // (t, n)
  __shared__ unsigned short lP[64][136];   // (p, n)
  __shared__ float lda[256];
  const int tid = threadIdx.x, lane = tid & 63, w = tid >> 6;
  {
    const int s = tid;
    lda[s] = dac[((size_t)b * LQ + cs + s) * NH + h];
    const f32x4* cr = reinterpret_cast<const f32x4*>(
        xbc + ((size_t)b * LQ + cs + s) * CONVD + DIN + NST);
#pragma unroll
    for (int n4 = 0; n4 < 32; n4++) {
      f32x4 v = cr[n4];
#pragma unroll
      for (int u = 0; u < 4; u++) lC[s][n4 * 4 + u] = f2bu(v[u]);
    }
  }
  if (tid < 64) {
    const f32x4* pr = reinterpret_cast<const f32x4*>(
        pv + ((size_t)((b * NCH + c) * NH + h)) * (HD * NST) + (size_t)tid * NST);
#pragma unroll
    for (int n4 = 0; n4 < 32; n4++) {
      f32x4 v = pr[n4];
#pragma unroll
      for (int u = 0; u < 4; u++) lP[tid][n4 * 4 + u] = f2bu(v[u]);
    }
  }
  __syncthreads();
  f32x4 acc[4][4] = {};
#pragma unroll
  for (int kk = 0; kk < 128; kk += 32) {
    short8 a[4], bb[4];
    const int ko = kk + ((lane >> 4) << 3);
#pragma unroll
    for (int i = 0; i < 4; i++) {
      a[i] = *reinterpret_cast<const short8*>(&lC[w * 64 + i * 16 + (lane & 15)][ko]);
      bb[i] = *reinterpret_cast<const short8*>(&lP[i * 16 + (lane & 15)][ko]);
    }
#pragma unroll
    for (int mi = 0; mi < 4; mi++)
#pragma unroll
      for (int ni = 0; ni < 4; ni++)
        acc[mi][ni] = mfma16(a[mi], bb[ni], acc[mi][ni]);
  }
  const float Dh = Dp[h];
#pragma unroll
  for (int mi = 0; mi < 4; mi++) {
    const int t = w * 64 + mi * 16 + ((lane >> 4) << 2);
#pragma unroll
    for (int ni = 0; ni < 4; ni++) {
      const int p = ni * 16 + (lane & 15);
#pragma unroll
      for (int v = 0; v < 4; v++) {
        const int tt = t + v;
        const size_t row = (size_t)b * LQ + cs + tt;
        const float scale = __expf(lda[tt]);
        const float xval = xbc[row * CONVD + h * HD + p];
        const size_t yi = row * DIN + h * HD + p;
        y[yi] += scale * acc[mi][ni][v] + Dh * xval;
      }
    }
  }
}

// ---------------- gate*silu + RMSNorm -> bf16 -------------------------------
__global__ __launch_bounds__(256) void k_gatenorm(
    const float* __restrict__ y, const unsigned short* __restrict__ gateb,
    const float* __restrict__ nw, unsigned short* __restrict__ hgb) {
  const int r = blockIdx.x;
  const int tid = threadIdx.x;
  const float* yr = y + (size_t)r * DIN;
  const unsigned short* gr = gateb + (size_t)r * DIN;
  float hg[16];
  float ss = 0.f;
#pragma unroll
  for (int j = 0; j < 16; j++) {
    const int d = tid + 256 * j;
    const float g = __bfloat162float(__builtin_bit_cast(__hip_bfloat16, gr[d]));
    const float v = yr[d] * (g / (1.f + __expf(-g)));
    hg[j] = v;
    ss += v * v;
  }
#pragma unroll
  for (int o = 32; o > 0; o >>= 1) ss += __shfl_down(ss, o);
  __shared__ float red[4];
  if ((tid & 63) == 0) red[tid >> 6] = ss;
  __syncthreads();
  const float tot = red[0] + red[1] + red[2] + red[3];
  const float scale = rsqrtf(tot / (float)DIN + 1e-5f);
#pragma unroll
  for (int j = 0; j < 16; j++) {
    const int d = tid + 256 * j;
    hgb[(size_t)r * DIN + d] = f2bu(hg[j] * scale * nw[d]);
  }
}

extern "C" void kernel_launch(void* const* d_in, const int* in_sizes, int n_in,
                              void* d_out, int out_size, void* d_ws, size_t ws_size,
                              hipStream_t stream) {
  const float* hidden = (const float*)d_in[0];
  const float* w1 = (const float*)d_in[1];
  const float* cw = (const float*)d_in[2];
  const float* cb = (const float*)d_in[3];
  const float* dtb = (const float*)d_in[4];
  const float* alog = (const float*)d_in[5];
  const float* Dp = (const float*)d_in[6];
  const float* nw = (const float*)d_in[7];
  const float* w2 = (const float*)d_in[8];
  float* out = (float*)d_out;
  char* ws = (char*)d_ws;

  // Lifetime-aliased layout (stages S1 casts+GEMM1 / S2 conv+dt / S3 ssd / S4
  // gatenorm / S5 GEMM2). Peak live = 245.4 MB < ws.
  const size_t OFF_GATEB = 0;            // bf16 4096x4096   S1-S4
  const size_t OFF_XBC = 33554432;       // f32 4096x4352    S2-S3
  const size_t OFF_DTV = 104857600;      // f32 4096x64      S2-S3
  const size_t OFF_DAC = 105906176;      // f32 4096x64      S2-S3
  const size_t OFF_CB = 106954752;       // f32 16x256x256   S3
  const size_t OFF_Y = 111149056;        // f32 4096x4096    S3-S4
  const size_t OFF_ST = 178257920;       // f32 1024x64x128  S3
  const size_t OFF_PV = 211812352;       // f32 1024x64x128  S3
  const size_t OFF_PROJX = 111149056;    // f32 4096x4416    S1-S2 (aliases Y+ST head)
  const size_t OFF_HB = 183500800;       // bf16 4096x2048   S1 (aliases ST tail)
  const size_t OFF_W1B = 200278016;      // bf16 8704x2048   S1 (aliases ST tail+PV)
  const size_t OFF_W2B = 0;              // bf16 2048x4096   S5 (aliases GATEB)
  const size_t OFF_HGB = 33554432;       // bf16 4096x4096   S4-S5 (aliases XBC)
  const size_t NEED = 245366784;
  if (ws_size < NEED) {
    fprintf(stderr, "WS TOO SMALL: %zu < %zu\n", ws_size, NEED);
    return;
  }
  unsigned short* gateb = (unsigned short*)(ws + OFF_GATEB);
  float* xbc = (float*)(ws + OFF_XBC);
  float* dtv = (float*)(ws + OFF_DTV);
  float* dac = (float*)(ws + OFF_DAC);
  float* cbuf = (float*)(ws + OFF_CB);
  float* y = (float*)(ws + OFF_Y);
  float* st = (float*)(ws + OFF_ST);
  float* pv = (float*)(ws + OFF_PV);
  float* projx = (float*)(ws + OFF_PROJX);
  unsigned short* hb = (unsigned short*)(ws + OFF_HB);
  unsigned short* w1b = (unsigned short*)(ws + OFF_W1B);
  unsigned short* w2b = (unsigned short*)(ws + OFF_W2B);
  unsigned short* hgb = (unsigned short*)(ws + OFF_HGB);

  // S1
  k_cast_pad<<<4096, 256, 0, stream>>>(hidden, hb, (long)BL * DMODEL, (long)BL * DMODEL);
  k_cast_pad<<<8192, 256, 0, stream>>>(w1, w1b, (long)PROJD * DMODEL, (long)PROJ_PAD2 * DMODEL);
  k_gemm256x128<true><<<dim3(PROJ_PAD2 / 128, BL / 256), 512, 0, stream>>>(
      hb, w1b, nullptr, gateb, projx, PROJD, DMODEL);
  // S2
  k_conv_silu<<<dim3(17, BL), 256, 0, stream>>>(projx, cw, cb, xbc);
  k_dt<<<16, 256, 0, stream>>>(projx, dtb, alog, dtv, dac);
  // S3
  k_cb<<<dim3(4, 16), 256, 0, stream>>>(xbc, cbuf);
  k_diag<<<dim3(NH, NCH, BB), 256, 0, stream>>>(xbc, dtv, dac, cbuf, y, st);
  k_scan<<<dim3(NH, BB), 256, 0, stream>>>(st, dac, pv);
  k_off<<<dim3(NH, NCH, BB), 256, 0, stream>>>(xbc, dac, pv, Dp, y);
  // S4
  k_gatenorm<<<BL, 256, 0, stream>>>(y, gateb, nw, hgb);
  // S5
  k_cast_pad<<<8192, 256, 0, stream>>>(w2, w2b, (long)DMODEL * DIN, (long)DMODEL * DIN);
  k_gemm256x128<false><<<dim3(DMODEL / 128, BL / 256), 512, 0, stream>>>(
      hgb, w2b, out, nullptr, nullptr, DMODEL, DIN);
}

// Round 7
// 655.472 us; speedup vs baseline: 1.2410x; 1.2410x over previous
//
#include <hip/hip_runtime.h>
#include <hip/hip_bf16.h>
#include <cstdio>

#define LQ 2048      // L
#define BB 2         // batch
#define BL 4096      // B*L rows
#define DMODEL 2048
#define DIN 4096
#define NH 64
#define HD 64
#define NST 128
#define CONVD 4352
#define PROJD 8512
#define PROJ_PAD2 8704   // pad to 256 multiple for 256-tile GEMM1
#define PXW 4416     // projx width: CONVD + NH
#define CHK 256
#define NCH 8        // chunks per batch

typedef __attribute__((ext_vector_type(8))) short short8;
typedef __attribute__((ext_vector_type(4))) float f32x4;

__device__ __forceinline__ unsigned short f2bu(float x) {
  __hip_bfloat16 h = __float2bfloat16(x);
  return __builtin_bit_cast(unsigned short, h);
}

__device__ __forceinline__ f32x4 mfma16(short8 a, short8 b, f32x4 c) {
  return __builtin_amdgcn_mfma_f32_16x16x32_bf16(a, b, c, 0, 0, 0);
}

#define GLD16(gptr, lptr)                                                  \
  __builtin_amdgcn_global_load_lds(                                        \
      (const __attribute__((address_space(1))) void*)(gptr),               \
      (__attribute__((address_space(3))) void*)(lptr), 16, 0, 0)

// ---------------- cast fp32 -> bf16 (with zero tail padding) ----------------
__global__ void k_cast_pad(const float* __restrict__ in, unsigned short* __restrict__ out,
                           long n, long ntot) {
  long i = (long)blockIdx.x * blockDim.x + threadIdx.x;
  long stride = (long)gridDim.x * blockDim.x;
  for (; i < ntot; i += stride)
    out[i] = (i < n) ? f2bu(in[i]) : (unsigned short)0;
}

// swizzled fragment read from a [256][64] bf16 LDS tile (involution: cg ^= row&7)
__device__ __forceinline__ short8 rdfrag(const unsigned short (*mp)[64], int rowbase,
                                         int lane, int kh) {
  const int row = rowbase + (lane & 15);
  const int cg = (((kh << 2) + (lane >> 4)) ^ (lane & 7)) << 3;
  return *reinterpret_cast<const short8*>(&mp[row][cg]);
}

// ==== 256x256 8-phase GEMM (R5 proven: 781 TF measured) ====================
template <bool SPLIT>
__global__ __launch_bounds__(512) void k_gemm256(
    const unsigned short* __restrict__ A, const unsigned short* __restrict__ Bw,
    float* __restrict__ C, unsigned short* __restrict__ gateb,
    float* __restrict__ projx, int Nreal, int K) {
  __shared__ unsigned short sh[2][2][256][64];  // [buf][A/B][row][col]
  const int tid = threadIdx.x;
  const int lane = tid & 63, w = tid >> 6;
  const int wm = w >> 2, wn2 = w & 3;
  const int gx = gridDim.x;
  const int nwg = gx * gridDim.y;
  const int bid = blockIdx.y * gx + blockIdx.x;
  const int qq = nwg >> 3;
  const int swz = (bid & 7) * qq + (bid >> 3);
  const int m0 = (swz / gx) * 256, n0 = (swz % gx) * 256;
  const int srow = tid >> 3;
  const int sdst = (tid & 7) * 8;                       // linear LDS col
  const int ssrc = ((tid & 7) ^ ((tid >> 3) & 7)) * 8;  // swizzled gmem col
  const unsigned short* Ab = A + (size_t)m0 * K;
  const unsigned short* Bb = Bw + (size_t)n0 * K;

#define ST(bf, mt, MP, r0, kk)                                             \
  GLD16(MP + (size_t)((r0) + srow) * K + (kk) + ssrc,                      \
        &sh[bf][mt][(r0) + srow][sdst])

  f32x4 acc[8][4] = {};
  const int nt = K >> 6;

  // prologue: stage tile 0 fully, in canonical round order
  ST(0, 0, Ab, 0, 0);   ST(0, 0, Ab, 128, 0);
  ST(0, 1, Bb, 0, 0);   ST(0, 1, Bb, 64, 0);
  ST(0, 1, Bb, 128, 0); ST(0, 1, Bb, 192, 0);
  ST(0, 0, Ab, 64, 0);  ST(0, 0, Ab, 192, 0);

#define DO_PHASE(P)                                                        \
  {                                                                        \
    const int rb = wm * 128 + (P) * 32;                                    \
    short8 a00 = rdfrag(sh[cur][0], rb, lane, 0);                          \
    short8 a01 = rdfrag(sh[cur][0], rb, lane, 1);                          \
    short8 a10 = rdfrag(sh[cur][0], rb + 16, lane, 0);                     \
    short8 a11 = rdfrag(sh[cur][0], rb + 16, lane, 1);                     \
    __builtin_amdgcn_s_setprio(1);                                         \
    _Pragma("unroll")                                                      \
    for (int nf = 0; nf < 4; nf++) {                                       \
      acc[2 * (P)][nf] = mfma16(a00, bfr[nf][0], acc[2 * (P)][nf]);        \
      acc[2 * (P)][nf] = mfma16(a01, bfr[nf][1], acc[2 * (P)][nf]);        \
      acc[2 * (P) + 1][nf] = mfma16(a10, bfr[nf][0], acc[2 * (P) + 1][nf]);\
      acc[2 * (P) + 1][nf] = mfma16(a11, bfr[nf][1], acc[2 * (P) + 1][nf]);\
    }                                                                      \
    __builtin_amdgcn_s_setprio(0);                                         \
  }

  for (int t = 0; t < nt; ++t) {
    const int cur = t & 1, nxt = cur ^ 1;
    const int kbn = (t + 1) << 6;
    const bool more = (t + 1 < nt);
    // entry: tile t rounds 0..5 (A0,A2,B0..B3) landed globally
    asm volatile("s_waitcnt vmcnt(2)" ::: "memory");
    __builtin_amdgcn_s_barrier();
    // ---- phase 0: stage A0,A2 of t+1; read all B frags + A mf0,1
    if (more) { ST(nxt, 0, Ab, 0, kbn); ST(nxt, 0, Ab, 128, kbn); }
    short8 bfr[4][2];
#pragma unroll
    for (int nf = 0; nf < 4; nf++) {
      bfr[nf][0] = rdfrag(sh[cur][1], wn2 * 64 + nf * 16, lane, 0);
      bfr[nf][1] = rdfrag(sh[cur][1], wn2 * 64 + nf * 16, lane, 1);
    }
    DO_PHASE(0)
    __builtin_amdgcn_s_barrier();
    // ---- phase 1: stage B0,B1 of t+1; A mf2,3
    if (more) { ST(nxt, 1, Bb, 0, kbn); ST(nxt, 1, Bb, 64, kbn); }
    DO_PHASE(1)
    // mid wait: tile t rounds A1,A3 landed globally
    if (more) asm volatile("s_waitcnt vmcnt(4)" ::: "memory");
    else      asm volatile("s_waitcnt vmcnt(0)" ::: "memory");
    __builtin_amdgcn_s_barrier();
    // ---- phase 2: stage B2,B3 of t+1; A mf4,5
    if (more) { ST(nxt, 1, Bb, 128, kbn); ST(nxt, 1, Bb, 192, kbn); }
    DO_PHASE(2)
    __builtin_amdgcn_s_barrier();
    // ---- phase 3: stage A1,A3 of t+1; A mf6,7
    if (more) { ST(nxt, 0, Ab, 64, kbn); ST(nxt, 0, Ab, 192, kbn); }
    DO_PHASE(3)
    // no trailing barrier: next tile's entry vmcnt+barrier covers it
  }
#undef DO_PHASE
#undef ST

  // epilogue
#pragma unroll
  for (int mf = 0; mf < 8; mf++) {
    const int row = m0 + wm * 128 + mf * 16 + ((lane >> 4) << 2);
#pragma unroll
    for (int nf = 0; nf < 4; nf++) {
      const int col = n0 + wn2 * 64 + nf * 16 + (lane & 15);
      if (SPLIT) {
        if (col < DIN) {
#pragma unroll
          for (int v = 0; v < 4; v++)
            gateb[(size_t)(row + v) * DIN + col] = f2bu(acc[mf][nf][v]);
        } else if (col < PROJD) {
#pragma unroll
          for (int v = 0; v < 4; v++)
            projx[(size_t)(row + v) * PXW + (col - DIN)] = acc[mf][nf][v];
        }
      } else {
        if (col < Nreal) {
#pragma unroll
          for (int v = 0; v < 4; v++)
            C[(size_t)(row + v) * Nreal + col] = acc[mf][nf][v];
        }
      }
    }
  }
}

// ---- 128x128 bf16 GEMM (R4 proven) — used for GEMM2 (512 blocks, 2 rounds) -
__global__ __launch_bounds__(256) void k_gemm_bt(
    const unsigned short* __restrict__ A, const unsigned short* __restrict__ Bw,
    float* __restrict__ C, int Nreal, int K) {
  __shared__ unsigned short lA[128][64];
  __shared__ unsigned short lB[128][64];
  const int tid = threadIdx.x;
  const int lane = tid & 63, w = tid >> 6;
  const int gx = gridDim.x;
  const int nwg = gx * gridDim.y;
  const int bid = blockIdx.y * gx + blockIdx.x;
  const int qq = nwg >> 3;
  const int swz = (bid & 7) * qq + (bid >> 3);
  const int m0 = (swz / gx) * 128, n0 = (swz % gx) * 128;
  const int wr = (w >> 1) * 64, wc = (w & 1) * 64;
  const int sr = tid >> 3;
  const int sdst = (tid & 7) * 8;
  const int ssrc = ((tid & 7) ^ ((tid >> 3) & 7)) * 8;
  f32x4 acc[4][4] = {};
  for (int kb = 0; kb < K; kb += 64) {
#pragma unroll
    for (int i = 0; i < 4; i++) {
      const int r = sr + i * 32;
      GLD16(A + (size_t)(m0 + r) * K + kb + ssrc, &lA[r][sdst]);
      GLD16(Bw + (size_t)(n0 + r) * K + kb + ssrc, &lB[r][sdst]);
    }
    __syncthreads();
#pragma unroll
    for (int kk = 0; kk < 64; kk += 32) {
      short8 af[4], bf[4];
      const int cg = ((((kk >> 3) + (lane >> 4)) ^ (lane & 7)) << 3);
#pragma unroll
      for (int i = 0; i < 4; i++) {
        af[i] = *reinterpret_cast<const short8*>(&lA[wr + i * 16 + (lane & 15)][cg]);
        bf[i] = *reinterpret_cast<const short8*>(&lB[wc + i * 16 + (lane & 15)][cg]);
      }
#pragma unroll
      for (int mi = 0; mi < 4; mi++)
#pragma unroll
        for (int ni = 0; ni < 4; ni++)
          acc[mi][ni] = mfma16(af[mi], bf[ni], acc[mi][ni]);
    }
    __syncthreads();
  }
#pragma unroll
  for (int mi = 0; mi < 4; mi++) {
    const int row = m0 + wr + mi * 16 + ((lane >> 4) << 2);
#pragma unroll
    for (int ni = 0; ni < 4; ni++) {
      const int col = n0 + wc + ni * 16 + (lane & 15);
      if (col < Nreal) {
#pragma unroll
        for (int v = 0; v < 4; v++)
          C[(size_t)(row + v) * Nreal + col] = acc[mi][ni][v];
      }
    }
  }
}

// ---------------- causal depthwise conv (K=4) + SiLU ------------------------
__global__ __launch_bounds__(256) void k_conv_silu(
    const float* __restrict__ projx, const float* __restrict__ cw,
    const float* __restrict__ cb, float* __restrict__ xbc) {
  const int ch = blockIdx.x * 256 + threadIdx.x;  // 17*256 = 4352 exact
  const int bt = blockIdx.y;
  const int b = bt >> 11, t = bt & 2047;
  float acc = cb[ch];
#pragma unroll
  for (int i = 0; i < 4; i++) {
    int tt = t - 3 + i;
    if (tt >= 0)
      acc += cw[ch * 4 + i] * projx[((size_t)b * LQ + tt) * PXW + ch];
  }
  float o = acc / (1.f + __expf(-acc));
  xbc[(size_t)bt * CONVD + ch] = o;
}

// ------- dt softplus + per-chunk cumsum(dt*A): parallel 2-phase scan --------
__global__ __launch_bounds__(256) void k_dt(
    const float* __restrict__ projx, const float* __restrict__ dtb,
    const float* __restrict__ alog, float* __restrict__ dtv,
    float* __restrict__ dac) {
  const int bc = blockIdx.x;  // 16 = b*8+c
  const int b = bc >> 3, c = bc & 7;
  const int h = threadIdx.x & 63, q = threadIdx.x >> 6;
  const float bias = dtb[h];
  const float Ah = -__expf(alog[h]);
  const size_t base = (size_t)b * LQ + c * CHK + q * 64;
  float vals[64];
  float part = 0.f;
#pragma unroll
  for (int j = 0; j < 64; j++) {
    float raw = projx[(base + j) * PXW + CONVD + h] + bias;
    float dt = raw > 20.f ? raw : log1pf(__expf(raw));
    vals[j] = dt;
    dtv[(base + j) * NH + h] = dt;
    part += dt;
  }
  __shared__ float partials[4][64];
  partials[q][h] = part;
  __syncthreads();
  float cum = 0.f;
  for (int qq = 0; qq < q; qq++) cum += partials[qq][h];
  cum *= Ah;
#pragma unroll
  for (int j = 0; j < 64; j++) {
    cum += vals[j] * Ah;
    dac[(base + j) * NH + h] = cum;
  }
}

// ---------------- CB[t][s] = sum_n C[t][n]*B[s][n] per (b,c) ----------------
__global__ __launch_bounds__(256) void k_cb(const float* __restrict__ xbc,
                                            float* __restrict__ cbuf) {
  const int q = blockIdx.x;   // 4 quadrants
  const int bc = blockIdx.y;  // 16
  const int b = bc >> 3, c = bc & 7;
  const int qt = q >> 1, qs = q & 1;
  __shared__ unsigned short lC[128][136];
  __shared__ unsigned short lB[128][136];
  const int tid = threadIdx.x, lane = tid & 63, w = tid >> 6;
  {
    int r = tid >> 1, hf = tid & 1;
    size_t rowc = (size_t)b * LQ + c * CHK + qt * 128 + r;
    const float* crp = xbc + rowc * CONVD + DIN + NST + hf * 64;
    size_t rowb = (size_t)b * LQ + c * CHK + qs * 128 + r;
    const float* brp = xbc + rowb * CONVD + DIN + hf * 64;
#pragma unroll
    for (int n = 0; n < 64; n++) {
      lC[r][hf * 64 + n] = f2bu(crp[n]);
      lB[r][hf * 64 + n] = f2bu(brp[n]);
    }
  }
  __syncthreads();
  const int wr = (w >> 1) * 64, wc = (w & 1) * 64;
  f32x4 acc[4][4] = {};
#pragma unroll
  for (int kk = 0; kk < 128; kk += 32) {
    short8 a[4], bb[4];
    const int ko = kk + ((lane >> 4) << 3);
#pragma unroll
    for (int i = 0; i < 4; i++) {
      a[i] = *reinterpret_cast<const short8*>(&lC[wr + i * 16 + (lane & 15)][ko]);
      bb[i] = *reinterpret_cast<const short8*>(&lB[wc + i * 16 + (lane & 15)][ko]);
    }
#pragma unroll
    for (int mi = 0; mi < 4; mi++)
#pragma unroll
      for (int ni = 0; ni < 4; ni++)
        acc[mi][ni] = mfma16(a[mi], bb[ni], acc[mi][ni]);
  }
  float* outp = cbuf + (size_t)bc * (CHK * CHK);
#pragma unroll
  for (int mi = 0; mi < 4; mi++) {
    const int t = qt * 128 + wr + mi * 16 + ((lane >> 4) << 2);
#pragma unroll
    for (int ni = 0; ni < 4; ni++) {
      const int s = qs * 128 + wc + ni * 16 + (lane & 15);
#pragma unroll
      for (int v = 0; v < 4; v++)
        outp[(size_t)(t + v) * CHK + s] = acc[mi][ni][v];
    }
  }
}

// ---------------- fused Y_diag + states per (b,c,h) -------------------------
// s processed in two halves of 128 -> LDS 72KB -> 2 blocks/CU (was 123KB/1).
__global__ __launch_bounds__(256) void k_diag(
    const float* __restrict__ xbc, const float* __restrict__ dtv,
    const float* __restrict__ dac, const float* __restrict__ cbuf,
    float* __restrict__ y, float* __restrict__ st) {
  const int h = blockIdx.x, c = blockIdx.y, b = blockIdx.z;
  const int cs = c * CHK;
  __shared__ unsigned short lXt[64][136];   // (p, s_loc) x*dt, bf16
  __shared__ unsigned short lBt[128][136];  // (n, s_loc) B*decay, bf16
  __shared__ unsigned short lS[256][40];    // (t, s-block32) masked S, bf16
  __shared__ float lda[256];
  const int tid = threadIdx.x, lane = tid & 63, w = tid >> 6;
  lda[tid] = dac[((size_t)b * LQ + cs + tid) * NH + h];
  __syncthreads();
  const float dalast = lda[255];
  const float* cbp = cbuf + ((size_t)(b * NCH + c)) * (CHK * CHK);
  const float da_t = lda[tid];
  f32x4 accY[4][4] = {};
  f32x4 accS[4][2] = {};
  const int wn = w * 32;
  const int sl = tid & 127, sub = tid >> 7;  // 2 threads per s-value
  for (int half = 0; half < 2; half++) {
    {
      const int s = half * 128 + sl;
      const size_t row = (size_t)b * LQ + cs + s;
      const float* xrow = xbc + row * CONVD;
      const float dts = dtv[row * NH + h];
      const float dec = __expf(dalast - lda[s]);
      const f32x4* x4 = reinterpret_cast<const f32x4*>(xrow + h * HD + sub * 32);
#pragma unroll
      for (int p4 = 0; p4 < 8; p4++) {
        f32x4 v = x4[p4];
#pragma unroll
        for (int u = 0; u < 4; u++) lXt[sub * 32 + p4 * 4 + u][sl] = f2bu(v[u] * dts);
      }
      const f32x4* b4 = reinterpret_cast<const f32x4*>(xrow + DIN + sub * 64);
#pragma unroll
      for (int n4 = 0; n4 < 16; n4++) {
        f32x4 v = b4[n4];
#pragma unroll
        for (int u = 0; u < 4; u++) lBt[sub * 64 + n4 * 4 + u][sl] = f2bu(v[u] * dec);
      }
    }
    __syncthreads();
    for (int sb4 = 0; sb4 < 4; sb4++) {
      const int sb = half * 4 + sb4;
      {
        const int t = tid;
        const f32x4* cr = reinterpret_cast<const f32x4*>(cbp + (size_t)t * CHK + sb * 32);
        f32x4 vv[8];
#pragma unroll
        for (int j4 = 0; j4 < 8; j4++) vv[j4] = cr[j4];
#pragma unroll
        for (int g = 0; g < 4; g++) {
          short8 pk;
#pragma unroll
          for (int e = 0; e < 8; e++) {
            const int j = g * 8 + e;
            const int s = sb * 32 + j;
            const float x = vv[j >> 2][j & 3];
            const float val = (s <= t) ? x * __expf(da_t - lda[s]) : 0.f;
            pk[e] = (short)f2bu(val);
          }
          *reinterpret_cast<short8*>(&lS[t][g * 8]) = pk;
        }
      }
      __syncthreads();
      short8 sf[4], xf[4], btf[2];
      const int ko = ((lane >> 4) << 3);
      const int so = sb4 * 32 + ko;
#pragma unroll
      for (int i = 0; i < 4; i++) {
        sf[i] = *reinterpret_cast<const short8*>(&lS[w * 64 + i * 16 + (lane & 15)][ko]);
        xf[i] = *reinterpret_cast<const short8*>(&lXt[i * 16 + (lane & 15)][so]);
      }
#pragma unroll
      for (int i = 0; i < 2; i++)
        btf[i] = *reinterpret_cast<const short8*>(&lBt[wn + i * 16 + (lane & 15)][so]);
#pragma unroll
      for (int mi = 0; mi < 4; mi++)
#pragma unroll
        for (int ni = 0; ni < 4; ni++)
          accY[mi][ni] = mfma16(sf[mi], xf[ni], accY[mi][ni]);
#pragma unroll
      for (int mi = 0; mi < 4; mi++)
#pragma unroll
        for (int nj = 0; nj < 2; nj++)
          accS[mi][nj] = mfma16(xf[mi], btf[nj], accS[mi][nj]);
      __syncthreads();
    }
  }
#pragma unroll
  for (int mi = 0; mi < 4; mi++) {
    const int t = w * 64 + mi * 16 + ((lane >> 4) << 2);
#pragma unroll
    for (int ni = 0; ni < 4; ni++) {
      const int p = ni * 16 + (lane & 15);
#pragma unroll
      for (int v = 0; v < 4; v++)
        y[((size_t)b * LQ + cs + t + v) * DIN + h * HD + p] = accY[mi][ni][v];
    }
  }
  float* stp = st + ((size_t)((b * NCH + c) * NH + h)) * (HD * NST);
#pragma unroll
  for (int mi = 0; mi < 4; mi++) {
    const int p = mi * 16 + ((lane >> 4) << 2);
#pragma unroll
    for (int nj = 0; nj < 2; nj++) {
      const int n = wn + nj * 16 + (lane & 15);
#pragma unroll
      for (int v = 0; v < 4; v++)
        stp[(size_t)(p + v) * NST + n] = accS[mi][nj][v];
    }
  }
}

// ---------------- inter-chunk state scan ------------------------------------
__global__ void k_scan(const float* __restrict__ st, const float* __restrict__ dac,
                       float* __restrict__ pv) {
  const int h = blockIdx.x, b = blockIdx.y;
  const int tid = threadIdx.x;
  float P[32];
#pragma unroll
  for (int j = 0; j < 32; j++) P[j] = 0.f;
  for (int c = 0; c < NCH; c++) {
    const size_t base = ((size_t)((b * NCH + c) * NH + h)) * (HD * NST);
#pragma unroll
    for (int j = 0; j < 32; j++) pv[base + tid + 256 * j] = P[j];
    const float d = __expf(dac[((size_t)b * LQ + c * CHK + 255) * NH + h]);
#pragma unroll
    for (int j = 0; j < 32; j++) P[j] = P[j] * d + st[base + tid + 256 * j];
  }
}

// ---------------- Y_off + D*x accumulate into y -----------------------------
// t-extent 128 per block (grid y = c*2 + th) -> LDS 51.5KB -> 3 blocks/CU.
__global__ __launch_bounds__(256) void k_off(
    const float* __restrict__ xbc, const float* __restrict__ dac,
    const float* __restrict__ pv, const float* __restrict__ Dp,
    float* __restrict__ y) {
  const int h = blockIdx.x;
  const int cth = blockIdx.y;
  const int c = cth >> 1, th = cth & 1;
  const int b = blockIdx.z;
  const int cs = c * CHK, t0 = th * 128;
  __shared__ unsigned short lC[128][136];  // (t_loc, n)
  __shared__ unsigned short lP[64][136];   // (p, n)
  __shared__ float lda[128];
  const int tid = threadIdx.x, lane = tid & 63, w = tid >> 6;
  const int wt = w >> 1, wp = w & 1;
  {
    const int r = tid >> 1, hf = tid & 1;
    const size_t row = (size_t)b * LQ + cs + t0 + r;
    if (hf == 0) lda[r] = dac[row * NH + h];
    const f32x4* cr = reinterpret_cast<const f32x4*>(
        xbc + row * CONVD + DIN + NST + hf * 64);
#pragma unroll
    for (int n4 = 0; n4 < 16; n4++) {
      f32x4 v = cr[n4];
#pragma unroll
      for (int u = 0; u < 4; u++) lC[r][hf * 64 + n4 * 4 + u] = f2bu(v[u]);
    }
  }
  if (tid < 64) {
    const f32x4* pr = reinterpret_cast<const f32x4*>(
        pv + ((size_t)((b * NCH + c) * NH + h)) * (HD * NST) + (size_t)tid * NST);
#pragma unroll
    for (int n4 = 0; n4 < 32; n4++) {
      f32x4 v = pr[n4];
#pragma unroll
      for (int u = 0; u < 4; u++) lP[tid][n4 * 4 + u] = f2bu(v[u]);
    }
  }
  __syncthreads();
  f32x4 acc[4][2] = {};
#pragma unroll
  for (int kk = 0; kk < 128; kk += 32) {
    short8 a[4], bb[2];
    const int ko = kk + ((lane >> 4) << 3);
#pragma unroll
    for (int i = 0; i < 4; i++)
      a[i] = *reinterpret_cast<const short8*>(&lC[wt * 64 + i * 16 + (lane & 15)][ko]);
#pragma unroll
    for (int j = 0; j < 2; j++)
      bb[j] = *reinterpret_cast<const short8*>(&lP[wp * 32 + j * 16 + (lane & 15)][ko]);
#pragma unroll
    for (int mi = 0; mi < 4; mi++)
#pragma unroll
      for (int nj = 0; nj < 2; nj++)
        acc[mi][nj] = mfma16(a[mi], bb[nj], acc[mi][nj]);
  }
  const float Dh = Dp[h];
#pragma unroll
  for (int mi = 0; mi < 4; mi++) {
    const int tl = wt * 64 + mi * 16 + ((lane >> 4) << 2);
#pragma unroll
    for (int nj = 0; nj < 2; nj++) {
      const int p = wp * 32 + nj * 16 + (lane & 15);
#pragma unroll
      for (int v = 0; v < 4; v++) {
        const int tt = tl + v;
        const size_t row = (size_t)b * LQ + cs + t0 + tt;
        const float scale = __expf(lda[tt]);
        const float xval = xbc[row * CONVD + h * HD + p];
        const size_t yi = row * DIN + h * HD + p;
        y[yi] += scale * acc[mi][nj][v] + Dh * xval;
      }
    }
  }
}

// ---------------- gate*silu + RMSNorm -> bf16 -------------------------------
__global__ __launch_bounds__(256) void k_gatenorm(
    const float* __restrict__ y, const unsigned short* __restrict__ gateb,
    const float* __restrict__ nw, unsigned short* __restrict__ hgb) {
  const int r = blockIdx.x;
  const int tid = threadIdx.x;
  const float* yr = y + (size_t)r * DIN;
  const unsigned short* gr = gateb + (size_t)r * DIN;
  float hg[16];
  float ss = 0.f;
#pragma unroll
  for (int j = 0; j < 16; j++) {
    const int d = tid + 256 * j;
    const float g = __bfloat162float(__builtin_bit_cast(__hip_bfloat16, gr[d]));
    const float v = yr[d] * (g / (1.f + __expf(-g)));
    hg[j] = v;
    ss += v * v;
  }
#pragma unroll
  for (int o = 32; o > 0; o >>= 1) ss += __shfl_down(ss, o);
  __shared__ float red[4];
  if ((tid & 63) == 0) red[tid >> 6] = ss;
  __syncthreads();
  const float tot = red[0] + red[1] + red[2] + red[3];
  const float scale = rsqrtf(tot / (float)DIN + 1e-5f);
#pragma unroll
  for (int j = 0; j < 16; j++) {
    const int d = tid + 256 * j;
    hgb[(size_t)r * DIN + d] = f2bu(hg[j] * scale * nw[d]);
  }
}

extern "C" void kernel_launch(void* const* d_in, const int* in_sizes, int n_in,
                              void* d_out, int out_size, void* d_ws, size_t ws_size,
                              hipStream_t stream) {
  const float* hidden = (const float*)d_in[0];
  const float* w1 = (const float*)d_in[1];
  const float* cw = (const float*)d_in[2];
  const float* cb = (const float*)d_in[3];
  const float* dtb = (const float*)d_in[4];
  const float* alog = (const float*)d_in[5];
  const float* Dp = (const float*)d_in[6];
  const float* nw = (const float*)d_in[7];
  const float* w2 = (const float*)d_in[8];
  float* out = (float*)d_out;
  char* ws = (char*)d_ws;

  // Lifetime-aliased layout (stages S1 casts+GEMM1 / S2 conv+dt / S3 ssd / S4
  // gatenorm / S5 GEMM2). Peak live = 245.4 MB < ws.
  const size_t OFF_GATEB = 0;            // bf16 4096x4096   S1-S4
  const size_t OFF_XBC = 33554432;       // f32 4096x4352    S2-S3
  const size_t OFF_DTV = 104857600;      // f32 4096x64      S2-S3
  const size_t OFF_DAC = 105906176;      // f32 4096x64      S2-S3
  const size_t OFF_CB = 106954752;       // f32 16x256x256   S3
  const size_t OFF_Y = 111149056;        // f32 4096x4096    S3-S4
  const size_t OFF_ST = 178257920;       // f32 1024x64x128  S3
  const size_t OFF_PV = 211812352;       // f32 1024x64x128  S3
  const size_t OFF_PROJX = 111149056;    // f32 4096x4416    S1-S2 (aliases Y+ST head)
  const size_t OFF_HB = 183500800;       // bf16 4096x2048   S1 (aliases ST tail)
  const size_t OFF_W1B = 200278016;      // bf16 8704x2048   S1 (aliases ST tail+PV)
  const size_t OFF_W2B = 0;              // bf16 2048x4096   S5 (aliases GATEB)
  const size_t OFF_HGB = 33554432;       // bf16 4096x4096   S4-S5 (aliases XBC)
  const size_t NEED = 245366784;
  if (ws_size < NEED) {
    fprintf(stderr, "WS TOO SMALL: %zu < %zu\n", ws_size, NEED);
    return;
  }
  unsigned short* gateb = (unsigned short*)(ws + OFF_GATEB);
  float* xbc = (float*)(ws + OFF_XBC);
  float* dtv = (float*)(ws + OFF_DTV);
  float* dac = (float*)(ws + OFF_DAC);
  float* cbuf = (float*)(ws + OFF_CB);
  float* y = (float*)(ws + OFF_Y);
  float* st = (float*)(ws + OFF_ST);
  float* pv = (float*)(ws + OFF_PV);
  float* projx = (float*)(ws + OFF_PROJX);
  unsigned short* hb = (unsigned short*)(ws + OFF_HB);
  unsigned short* w1b = (unsigned short*)(ws + OFF_W1B);
  unsigned short* w2b = (unsigned short*)(ws + OFF_W2B);
  unsigned short* hgb = (unsigned short*)(ws + OFF_HGB);

  // S1
  k_cast_pad<<<4096, 256, 0, stream>>>(hidden, hb, (long)BL * DMODEL, (long)BL * DMODEL);
  k_cast_pad<<<8192, 256, 0, stream>>>(w1, w1b, (long)PROJD * DMODEL, (long)PROJ_PAD2 * DMODEL);
  k_gemm256<true><<<dim3(PROJ_PAD2 / 256, BL / 256), 512, 0, stream>>>(
      hb, w1b, nullptr, gateb, projx, PROJD, DMODEL);
  // S2
  k_conv_silu<<<dim3(17, BL), 256, 0, stream>>>(projx, cw, cb, xbc);
  k_dt<<<16, 256, 0, stream>>>(projx, dtb, alog, dtv, dac);
  // S3
  k_cb<<<dim3(4, 16), 256, 0, stream>>>(xbc, cbuf);
  k_diag<<<dim3(NH, NCH, BB), 256, 0, stream>>>(xbc, dtv, dac, cbuf, y, st);
  k_scan<<<dim3(NH, BB), 256, 0, stream>>>(st, dac, pv);
  k_off<<<dim3(NH, NCH * 2, BB), 256, 0, stream>>>(xbc, dac, pv, Dp, y);
  // S4
  k_gatenorm<<<BL, 256, 0, stream>>>(y, gateb, nw, hgb);
  // S5
  k_cast_pad<<<8192, 256, 0, stream>>>(w2, w2b, (long)DMODEL * DIN, (long)DMODEL * DIN);
  k_gemm_bt<<<dim3(DMODEL / 128, BL / 128), 256, 0, stream>>>(
      hgb, w2b, out, DMODEL, DIN);
}

// Round 9
// 630.702 us; speedup vs baseline: 1.2897x; 1.0393x over previous
//
#include <hip/hip_runtime.h>
#include <hip/hip_bf16.h>
#include <cstdio>

#define LQ 2048      // L
#define BB 2         // batch
#define BL 4096      // B*L rows
#define DMODEL 2048
#define DIN 4096
#define NH 64
#define HD 64
#define NST 128
#define CONVD 4352
#define PROJD 8512
#define PROJ_PAD2 8704   // pad to 256 multiple for 256-tile GEMM1
#define PXW 4416     // projx width: CONVD + NH
#define CHK 256
#define NCH 8        // chunks per batch

typedef __attribute__((ext_vector_type(8))) short short8;
typedef __attribute__((ext_vector_type(4))) float f32x4;

__device__ __forceinline__ unsigned short f2bu(float x) {
  __hip_bfloat16 h = __float2bfloat16(x);
  return __builtin_bit_cast(unsigned short, h);
}

__device__ __forceinline__ f32x4 mfma16(short8 a, short8 b, f32x4 c) {
  return __builtin_amdgcn_mfma_f32_16x16x32_bf16(a, b, c, 0, 0, 0);
}

#define GLD16(gptr, lptr)                                                  \
  __builtin_amdgcn_global_load_lds(                                        \
      (const __attribute__((address_space(1))) void*)(gptr),               \
      (__attribute__((address_space(3))) void*)(lptr), 16, 0, 0)

// ------- fused vectorized cast fp32 -> bf16 for hb / w1b(+pad) / w2b --------
__global__ void k_cast3(const float* __restrict__ s0, unsigned short* __restrict__ d0,
                        long n0,
                        const float* __restrict__ s1, unsigned short* __restrict__ d1,
                        long n1r, long n1t,
                        const float* __restrict__ s2, unsigned short* __restrict__ d2,
                        long n2) {
  const long ntot8 = (n0 + n1t + n2) >> 3;
  long i = (long)blockIdx.x * blockDim.x + threadIdx.x;
  const long stride = (long)gridDim.x * blockDim.x;
  for (; i < ntot8; i += stride) {
    const long e = i << 3;
    const float* src;
    unsigned short* dst;
    long rel, nreal;
    if (e < n0) { src = s0; dst = d0; rel = e; nreal = n0; }
    else if (e < n0 + n1t) { src = s1; dst = d1; rel = e - n0; nreal = n1r; }
    else { src = s2; dst = d2; rel = e - n0 - n1t; nreal = n2; }
    short8 pk;
    if (rel + 8 <= nreal) {
      const f32x4* sp = reinterpret_cast<const f32x4*>(src + rel);
      f32x4 v0 = sp[0], v1 = sp[1];
#pragma unroll
      for (int u = 0; u < 4; u++) {
        pk[u] = (short)f2bu(v0[u]);
        pk[4 + u] = (short)f2bu(v1[u]);
      }
    } else {
#pragma unroll
      for (int u = 0; u < 8; u++)
        pk[u] = (rel + u < nreal) ? (short)f2bu(src[rel + u]) : (short)0;
    }
    *reinterpret_cast<short8*>(dst + rel) = pk;
  }
}

// swizzled fragment read from a [256][64] bf16 LDS tile (involution: cg ^= row&7)
__device__ __forceinline__ short8 rdfrag(const unsigned short (*mp)[64], int rowbase,
                                         int lane, int kh) {
  const int row = rowbase + (lane & 15);
  const int cg = (((kh << 2) + (lane >> 4)) ^ (lane & 7)) << 3;
  return *reinterpret_cast<const short8*>(&mp[row][cg]);
}

// ==== 256x256 8-phase GEMM (R5 proven: 781 TF measured) ====================
template <bool SPLIT>
__global__ __launch_bounds__(512) void k_gemm256(
    const unsigned short* __restrict__ A, const unsigned short* __restrict__ Bw,
    float* __restrict__ C, unsigned short* __restrict__ gateb,
    float* __restrict__ projx, int Nreal, int K) {
  __shared__ unsigned short sh[2][2][256][64];  // [buf][A/B][row][col]
  const int tid = threadIdx.x;
  const int lane = tid & 63, w = tid >> 6;
  const int wm = w >> 2, wn2 = w & 3;
  const int gx = gridDim.x;
  const int nwg = gx * gridDim.y;
  const int bid = blockIdx.y * gx + blockIdx.x;
  const int qq = nwg >> 3;
  const int swz = (bid & 7) * qq + (bid >> 3);
  const int m0 = (swz / gx) * 256, n0 = (swz % gx) * 256;
  const int srow = tid >> 3;
  const int sdst = (tid & 7) * 8;                       // linear LDS col
  const int ssrc = ((tid & 7) ^ ((tid >> 3) & 7)) * 8;  // swizzled gmem col
  const unsigned short* Ab = A + (size_t)m0 * K;
  const unsigned short* Bb = Bw + (size_t)n0 * K;

#define ST(bf, mt, MP, r0, kk)                                             \
  GLD16(MP + (size_t)((r0) + srow) * K + (kk) + ssrc,                      \
        &sh[bf][mt][(r0) + srow][sdst])

  f32x4 acc[8][4] = {};
  const int nt = K >> 6;

  // prologue: stage tile 0 fully, in canonical round order
  ST(0, 0, Ab, 0, 0);   ST(0, 0, Ab, 128, 0);
  ST(0, 1, Bb, 0, 0);   ST(0, 1, Bb, 64, 0);
  ST(0, 1, Bb, 128, 0); ST(0, 1, Bb, 192, 0);
  ST(0, 0, Ab, 64, 0);  ST(0, 0, Ab, 192, 0);

#define DO_PHASE(P)                                                        \
  {                                                                        \
    const int rb = wm * 128 + (P) * 32;                                    \
    short8 a00 = rdfrag(sh[cur][0], rb, lane, 0);                          \
    short8 a01 = rdfrag(sh[cur][0], rb, lane, 1);                          \
    short8 a10 = rdfrag(sh[cur][0], rb + 16, lane, 0);                     \
    short8 a11 = rdfrag(sh[cur][0], rb + 16, lane, 1);                     \
    __builtin_amdgcn_s_setprio(1);                                         \
    _Pragma("unroll")                                                      \
    for (int nf = 0; nf < 4; nf++) {                                       \
      acc[2 * (P)][nf] = mfma16(a00, bfr[nf][0], acc[2 * (P)][nf]);        \
      acc[2 * (P)][nf] = mfma16(a01, bfr[nf][1], acc[2 * (P)][nf]);        \
      acc[2 * (P) + 1][nf] = mfma16(a10, bfr[nf][0], acc[2 * (P) + 1][nf]);\
      acc[2 * (P) + 1][nf] = mfma16(a11, bfr[nf][1], acc[2 * (P) + 1][nf]);\
    }                                                                      \
    __builtin_amdgcn_s_setprio(0);                                         \
  }

  for (int t = 0; t < nt; ++t) {
    const int cur = t & 1, nxt = cur ^ 1;
    const int kbn = (t + 1) << 6;
    const bool more = (t + 1 < nt);
    // entry: tile t rounds 0..5 (A0,A2,B0..B3) landed globally
    asm volatile("s_waitcnt vmcnt(2)" ::: "memory");
    __builtin_amdgcn_s_barrier();
    // ---- phase 0: stage A0,A2 of t+1; read all B frags + A mf0,1
    if (more) { ST(nxt, 0, Ab, 0, kbn); ST(nxt, 0, Ab, 128, kbn); }
    short8 bfr[4][2];
#pragma unroll
    for (int nf = 0; nf < 4; nf++) {
      bfr[nf][0] = rdfrag(sh[cur][1], wn2 * 64 + nf * 16, lane, 0);
      bfr[nf][1] = rdfrag(sh[cur][1], wn2 * 64 + nf * 16, lane, 1);
    }
    DO_PHASE(0)
    __builtin_amdgcn_s_barrier();
    // ---- phase 1: stage B0,B1 of t+1; A mf2,3
    if (more) { ST(nxt, 1, Bb, 0, kbn); ST(nxt, 1, Bb, 64, kbn); }
    DO_PHASE(1)
    // mid wait: tile t rounds A1,A3 landed globally
    if (more) asm volatile("s_waitcnt vmcnt(4)" ::: "memory");
    else      asm volatile("s_waitcnt vmcnt(0)" ::: "memory");
    __builtin_amdgcn_s_barrier();
    // ---- phase 2: stage B2,B3 of t+1; A mf4,5
    if (more) { ST(nxt, 1, Bb, 128, kbn); ST(nxt, 1, Bb, 192, kbn); }
    DO_PHASE(2)
    __builtin_amdgcn_s_barrier();
    // ---- phase 3: stage A1,A3 of t+1; A mf6,7
    if (more) { ST(nxt, 0, Ab, 64, kbn); ST(nxt, 0, Ab, 192, kbn); }
    DO_PHASE(3)
    // no trailing barrier: next tile's entry vmcnt+barrier covers it
  }
#undef DO_PHASE
#undef ST

  // epilogue
#pragma unroll
  for (int mf = 0; mf < 8; mf++) {
    const int row = m0 + wm * 128 + mf * 16 + ((lane >> 4) << 2);
#pragma unroll
    for (int nf = 0; nf < 4; nf++) {
      const int col = n0 + wn2 * 64 + nf * 16 + (lane & 15);
      if (SPLIT) {
        if (col < DIN) {
#pragma unroll
          for (int v = 0; v < 4; v++)
            gateb[(size_t)(row + v) * DIN + col] = f2bu(acc[mf][nf][v]);
        } else if (col < PROJD) {
#pragma unroll
          for (int v = 0; v < 4; v++)
            projx[(size_t)(row + v) * PXW + (col - DIN)] = acc[mf][nf][v];
        }
      } else {
        if (col < Nreal) {
#pragma unroll
          for (int v = 0; v < 4; v++)
            C[(size_t)(row + v) * Nreal + col] = acc[mf][nf][v];
        }
      }
    }
  }
}

// ---- 128x128 bf16 GEMM (R4 proven) — used for GEMM2 (512 blocks, 2 rounds) -
__global__ __launch_bounds__(256) void k_gemm_bt(
    const unsigned short* __restrict__ A, const unsigned short* __restrict__ Bw,
    float* __restrict__ C, int Nreal, int K) {
  __shared__ unsigned short lA[128][64];
  __shared__ unsigned short lB[128][64];
  const int tid = threadIdx.x;
  const int lane = tid & 63, w = tid >> 6;
  const int gx = gridDim.x;
  const int nwg = gx * gridDim.y;
  const int bid = blockIdx.y * gx + blockIdx.x;
  const int qq = nwg >> 3;
  const int swz = (bid & 7) * qq + (bid >> 3);
  const int m0 = (swz / gx) * 128, n0 = (swz % gx) * 128;
  const int wr = (w >> 1) * 64, wc = (w & 1) * 64;
  const int sr = tid >> 3;
  const int sdst = (tid & 7) * 8;
  const int ssrc = ((tid & 7) ^ ((tid >> 3) & 7)) * 8;
  f32x4 acc[4][4] = {};
  for (int kb = 0; kb < K; kb += 64) {
#pragma unroll
    for (int i = 0; i < 4; i++) {
      const int r = sr + i * 32;
      GLD16(A + (size_t)(m0 + r) * K + kb + ssrc, &lA[r][sdst]);
      GLD16(Bw + (size_t)(n0 + r) * K + kb + ssrc, &lB[r][sdst]);
    }
    __syncthreads();
#pragma unroll
    for (int kk = 0; kk < 64; kk += 32) {
      short8 af[4], bf[4];
      const int cg = ((((kk >> 3) + (lane >> 4)) ^ (lane & 7)) << 3);
#pragma unroll
      for (int i = 0; i < 4; i++) {
        af[i] = *reinterpret_cast<const short8*>(&lA[wr + i * 16 + (lane & 15)][cg]);
        bf[i] = *reinterpret_cast<const short8*>(&lB[wc + i * 16 + (lane & 15)][cg]);
      }
#pragma unroll
      for (int mi = 0; mi < 4; mi++)
#pragma unroll
        for (int ni = 0; ni < 4; ni++)
          acc[mi][ni] = mfma16(af[mi], bf[ni], acc[mi][ni]);
    }
    __syncthreads();
  }
#pragma unroll
  for (int mi = 0; mi < 4; mi++) {
    const int row = m0 + wr + mi * 16 + ((lane >> 4) << 2);
#pragma unroll
    for (int ni = 0; ni < 4; ni++) {
      const int col = n0 + wc + ni * 16 + (lane & 15);
      if (col < Nreal) {
#pragma unroll
        for (int v = 0; v < 4; v++)
          C[(size_t)(row + v) * Nreal + col] = acc[mi][ni][v];
      }
    }
  }
}

// ---------------- causal depthwise conv (K=4) + SiLU ------------------------
__global__ __launch_bounds__(256) void k_conv_silu(
    const float* __restrict__ projx, const float* __restrict__ cw,
    const float* __restrict__ cb, float* __restrict__ xbc) {
  const int ch = blockIdx.x * 256 + threadIdx.x;  // 17*256 = 4352 exact
  const int bt = blockIdx.y;
  const int b = bt >> 11, t = bt & 2047;
  float acc = cb[ch];
#pragma unroll
  for (int i = 0; i < 4; i++) {
    int tt = t - 3 + i;
    if (tt >= 0)
      acc += cw[ch * 4 + i] * projx[((size_t)b * LQ + tt) * PXW + ch];
  }
  float o = acc / (1.f + __expf(-acc));
  xbc[(size_t)bt * CONVD + ch] = o;
}

// ------- dt softplus + per-chunk cumsum(dt*A): parallel 2-phase scan --------
__global__ __launch_bounds__(256) void k_dt(
    const float* __restrict__ projx, const float* __restrict__ dtb,
    const float* __restrict__ alog, float* __restrict__ dtv,
    float* __restrict__ dac) {
  const int bc = blockIdx.x;  // 16 = b*8+c
  const int b = bc >> 3, c = bc & 7;
  const int h = threadIdx.x & 63, q = threadIdx.x >> 6;
  const float bias = dtb[h];
  const float Ah = -__expf(alog[h]);
  const size_t base = (size_t)b * LQ + c * CHK + q * 64;
  float vals[64];
  float part = 0.f;
#pragma unroll
  for (int j = 0; j < 64; j++) {
    float raw = projx[(base + j) * PXW + CONVD + h] + bias;
    float dt = raw > 20.f ? raw : log1pf(__expf(raw));
    vals[j] = dt;
    dtv[(base + j) * NH + h] = dt;
    part += dt;
  }
  __shared__ float partials[4][64];
  partials[q][h] = part;
  __syncthreads();
  float cum = 0.f;
  for (int qq = 0; qq < q; qq++) cum += partials[qq][h];
  cum *= Ah;
#pragma unroll
  for (int j = 0; j < 64; j++) {
    cum += vals[j] * Ah;
    dac[(base + j) * NH + h] = cum;
  }
}

// ---------------- CB[t][s] = sum_n C[t][n]*B[s][n] per (b,c) ----------------
__global__ __launch_bounds__(256) void k_cb(const float* __restrict__ xbc,
                                            float* __restrict__ cbuf) {
  const int q = blockIdx.x;   // 4 quadrants
  const int bc = blockIdx.y;  // 16
  const int b = bc >> 3, c = bc & 7;
  const int qt = q >> 1, qs = q & 1;
  __shared__ unsigned short lC[128][136];
  __shared__ unsigned short lB[128][136];
  const int tid = threadIdx.x, lane = tid & 63, w = tid >> 6;
  {
    int r = tid >> 1, hf = tid & 1;
    size_t rowc = (size_t)b * LQ + c * CHK + qt * 128 + r;
    size_t rowb = (size_t)b * LQ + c * CHK + qs * 128 + r;
    const f32x4* crp = reinterpret_cast<const f32x4*>(
        xbc + rowc * CONVD + DIN + NST + hf * 64);
    const f32x4* brp = reinterpret_cast<const f32x4*>(
        xbc + rowb * CONVD + DIN + hf * 64);
#pragma unroll
    for (int n4 = 0; n4 < 16; n4++) {
      f32x4 vc = crp[n4], vb = brp[n4];
#pragma unroll
      for (int u = 0; u < 4; u++) {
        lC[r][hf * 64 + n4 * 4 + u] = f2bu(vc[u]);
        lB[r][hf * 64 + n4 * 4 + u] = f2bu(vb[u]);
      }
    }
  }
  __syncthreads();
  const int wr = (w >> 1) * 64, wc = (w & 1) * 64;
  f32x4 acc[4][4] = {};
#pragma unroll
  for (int kk = 0; kk < 128; kk += 32) {
    short8 a[4], bb[4];
    const int ko = kk + ((lane >> 4) << 3);
#pragma unroll
    for (int i = 0; i < 4; i++) {
      a[i] = *reinterpret_cast<const short8*>(&lC[wr + i * 16 + (lane & 15)][ko]);
      bb[i] = *reinterpret_cast<const short8*>(&lB[wc + i * 16 + (lane & 15)][ko]);
    }
#pragma unroll
    for (int mi = 0; mi < 4; mi++)
#pragma unroll
      for (int ni = 0; ni < 4; ni++)
        acc[mi][ni] = mfma16(a[mi], bb[ni], acc[mi][ni]);
  }
  float* outp = cbuf + (size_t)bc * (CHK * CHK);
#pragma unroll
  for (int mi = 0; mi < 4; mi++) {
    const int t = qt * 128 + wr + mi * 16 + ((lane >> 4) << 2);
#pragma unroll
    for (int ni = 0; ni < 4; ni++) {
      const int s = qs * 128 + wc + ni * 16 + (lane & 15);
#pragma unroll
      for (int v = 0; v < 4; v++)
        outp[(size_t)(t + v) * CHK + s] = acc[mi][ni][v];
    }
  }
}

// ---------------- fused Y_diag + states per (b,c,h) -------------------------
// s processed in two halves of 128 -> LDS 72KB -> 2 blocks/CU.
__global__ __launch_bounds__(256) void k_diag(
    const float* __restrict__ xbc, const float* __restrict__ dtv,
    const float* __restrict__ dac, const float* __restrict__ cbuf,
    float* __restrict__ y, float* __restrict__ st) {
  const int h = blockIdx.x, c = blockIdx.y, b = blockIdx.z;
  const int cs = c * CHK;
  __shared__ unsigned short lXt[64][136];   // (p, s_loc) x*dt, bf16
  __shared__ unsigned short lBt[128][136];  // (n, s_loc) B*decay, bf16
  __shared__ unsigned short lS[256][40];    // (t, s-block32) masked S, bf16
  __shared__ float lda[256];
  const int tid = threadIdx.x, lane = tid & 63, w = tid >> 6;
  lda[tid] = dac[((size_t)b * LQ + cs + tid) * NH + h];
  __syncthreads();
  const float dalast = lda[255];
  const float* cbp = cbuf + ((size_t)(b * NCH + c)) * (CHK * CHK);
  const float da_t = lda[tid];
  f32x4 accY[4][4] = {};
  f32x4 accS[4][2] = {};
  const int wn = w * 32;
  const int sl = tid & 127, sub = tid >> 7;  // 2 threads per s-value
  for (int half = 0; half < 2; half++) {
    {
      const int s = half * 128 + sl;
      const size_t row = (size_t)b * LQ + cs + s;
      const float* xrow = xbc + row * CONVD;
      const float dts = dtv[row * NH + h];
      const float dec = __expf(dalast - lda[s]);
      const f32x4* x4 = reinterpret_cast<const f32x4*>(xrow + h * HD + sub * 32);
#pragma unroll
      for (int p4 = 0; p4 < 8; p4++) {
        f32x4 v = x4[p4];
#pragma unroll
        for (int u = 0; u < 4; u++) lXt[sub * 32 + p4 * 4 + u][sl] = f2bu(v[u] * dts);
      }
      const f32x4* b4 = reinterpret_cast<const f32x4*>(xrow + DIN + sub * 64);
#pragma unroll
      for (int n4 = 0; n4 < 16; n4++) {
        f32x4 v = b4[n4];
#pragma unroll
        for (int u = 0; u < 4; u++) lBt[sub * 64 + n4 * 4 + u][sl] = f2bu(v[u] * dec);
      }
    }
    __syncthreads();
    for (int sb4 = 0; sb4 < 4; sb4++) {
      const int sb = half * 4 + sb4;
      {
        const int t = tid;
        const f32x4* cr = reinterpret_cast<const f32x4*>(cbp + (size_t)t * CHK + sb * 32);
        f32x4 vv[8];
#pragma unroll
        for (int j4 = 0; j4 < 8; j4++) vv[j4] = cr[j4];
#pragma unroll
        for (int g = 0; g < 4; g++) {
          short8 pk;
#pragma unroll
          for (int e = 0; e < 8; e++) {
            const int j = g * 8 + e;
            const int s = sb * 32 + j;
            const float x = vv[j >> 2][j & 3];
            const float val = (s <= t) ? x * __expf(da_t - lda[s]) : 0.f;
            pk[e] = (short)f2bu(val);
          }
          *reinterpret_cast<short8*>(&lS[t][g * 8]) = pk;
        }
      }
      __syncthreads();
      short8 sf[4], xf[4], btf[2];
      const int ko = ((lane >> 4) << 3);
      const int so = sb4 * 32 + ko;
#pragma unroll
      for (int i = 0; i < 4; i++) {
        sf[i] = *reinterpret_cast<const short8*>(&lS[w * 64 + i * 16 + (lane & 15)][ko]);
        xf[i] = *reinterpret_cast<const short8*>(&lXt[i * 16 + (lane & 15)][so]);
      }
#pragma unroll
      for (int i = 0; i < 2; i++)
        btf[i] = *reinterpret_cast<const short8*>(&lBt[wn + i * 16 + (lane & 15)][so]);
#pragma unroll
      for (int mi = 0; mi < 4; mi++)
#pragma unroll
        for (int ni = 0; ni < 4; ni++)
          accY[mi][ni] = mfma16(sf[mi], xf[ni], accY[mi][ni]);
#pragma unroll
      for (int mi = 0; mi < 4; mi++)
#pragma unroll
        for (int nj = 0; nj < 2; nj++)
          accS[mi][nj] = mfma16(xf[mi], btf[nj], accS[mi][nj]);
      __syncthreads();
    }
  }
#pragma unroll
  for (int mi = 0; mi < 4; mi++) {
    const int t = w * 64 + mi * 16 + ((lane >> 4) << 2);
#pragma unroll
    for (int ni = 0; ni < 4; ni++) {
      const int p = ni * 16 + (lane & 15);
#pragma unroll
      for (int v = 0; v < 4; v++)
        y[((size_t)b * LQ + cs + t + v) * DIN + h * HD + p] = accY[mi][ni][v];
    }
  }
  float* stp = st + ((size_t)((b * NCH + c) * NH + h)) * (HD * NST);
#pragma unroll
  for (int mi = 0; mi < 4; mi++) {
    const int p = mi * 16 + ((lane >> 4) << 2);
#pragma unroll
    for (int nj = 0; nj < 2; nj++) {
      const int n = wn + nj * 16 + (lane & 15);
#pragma unroll
      for (int v = 0; v < 4; v++)
        stp[(size_t)(p + v) * NST + n] = accS[mi][nj][v];
    }
  }
}

// ---------------- inter-chunk state scan (pv stored as bf16) ----------------
__global__ void k_scan(const float* __restrict__ st, const float* __restrict__ dac,
                       unsigned short* __restrict__ pv) {
  const int h = blockIdx.x, b = blockIdx.y;
  const int tid = threadIdx.x;
  float P[32];
#pragma unroll
  for (int j = 0; j < 32; j++) P[j] = 0.f;
  for (int c = 0; c < NCH; c++) {
    const size_t base = ((size_t)((b * NCH + c) * NH + h)) * (HD * NST);
#pragma unroll
    for (int j = 0; j < 32; j++) pv[base + tid + 256 * j] = f2bu(P[j]);
    const float d = __expf(dac[((size_t)b * LQ + c * CHK + 255) * NH + h]);
#pragma unroll
    for (int j = 0; j < 32; j++) P[j] = P[j] * d + st[base + tid + 256 * j];
  }
}

// ---------------- Y_off + D*x accumulate into y -----------------------------
// t-extent 128 per block (grid y = c*2 + th) -> LDS 51.5KB -> 3 blocks/CU.
__global__ __launch_bounds__(256) void k_off(
    const float* __restrict__ xbc, const float* __restrict__ dac,
    const unsigned short* __restrict__ pv, const float* __restrict__ Dp,
    float* __restrict__ y) {
  const int h = blockIdx.x;
  const int cth = blockIdx.y;
  const int c = cth >> 1, th = cth & 1;
  const int b = blockIdx.z;
  const int cs = c * CHK, t0 = th * 128;
  __shared__ unsigned short lC[128][136];  // (t_loc, n)
  __shared__ unsigned short lP[64][136];   // (p, n)
  __shared__ float lda[128];
  const int tid = threadIdx.x, lane = tid & 63, w = tid >> 6;
  const int wt = w >> 1, wp = w & 1;
  {
    const int r = tid >> 1, hf = tid & 1;
    const size_t row = (size_t)b * LQ + cs + t0 + r;
    if (hf == 0) lda[r] = dac[row * NH + h];
    const f32x4* cr = reinterpret_cast<const f32x4*>(
        xbc + row * CONVD + DIN + NST + hf * 64);
#pragma unroll
    for (int n4 = 0; n4 < 16; n4++) {
      f32x4 v = cr[n4];
#pragma unroll
      for (int u = 0; u < 4; u++) lC[r][hf * 64 + n4 * 4 + u] = f2bu(v[u]);
    }
  }
  if (tid < 64) {
    const unsigned short* pr =
        pv + ((size_t)((b * NCH + c) * NH + h)) * (HD * NST) + (size_t)tid * NST;
#pragma unroll
    for (int n8 = 0; n8 < 16; n8++)
      *reinterpret_cast<short8*>(&lP[tid][n8 * 8]) =
          *reinterpret_cast<const short8*>(pr + n8 * 8);
  }
  __syncthreads();
  f32x4 acc[4][2] = {};
#pragma unroll
  for (int kk = 0; kk < 128; kk += 32) {
    short8 a[4], bb[2];
    const int ko = kk + ((lane >> 4) << 3);
#pragma unroll
    for (int i = 0; i < 4; i++)
      a[i] = *reinterpret_cast<const short8*>(&lC[wt * 64 + i * 16 + (lane & 15)][ko]);
#pragma unroll
    for (int j = 0; j < 2; j++)
      bb[j] = *reinterpret_cast<const short8*>(&lP[wp * 32 + j * 16 + (lane & 15)][ko]);
#pragma unroll
    for (int mi = 0; mi < 4; mi++)
#pragma unroll
      for (int nj = 0; nj < 2; nj++)
        acc[mi][nj] = mfma16(a[mi], bb[nj], acc[mi][nj]);
  }
  const float Dh = Dp[h];
#pragma unroll
  for (int mi = 0; mi < 4; mi++) {
    const int tl = wt * 64 + mi * 16 + ((lane >> 4) << 2);
#pragma unroll
    for (int nj = 0; nj < 2; nj++) {
      const int p = wp * 32 + nj * 16 + (lane & 15);
#pragma unroll
      for (int v = 0; v < 4; v++) {
        const int tt = tl + v;
        const size_t row = (size_t)b * LQ + cs + t0 + tt;
        const float scale = __expf(lda[tt]);
        const float xval = xbc[row * CONVD + h * HD + p];
        const size_t yi = row * DIN + h * HD + p;
        y[yi] += scale * acc[mi][nj][v] + Dh * xval;
      }
    }
  }
}

// ---------------- gate*silu + RMSNorm -> bf16 -------------------------------
__global__ __launch_bounds__(256) void k_gatenorm(
    const float* __restrict__ y, const unsigned short* __restrict__ gateb,
    const float* __restrict__ nw, unsigned short* __restrict__ hgb) {
  const int r = blockIdx.x;
  const int tid = threadIdx.x;
  const float* yr = y + (size_t)r * DIN;
  const unsigned short* gr = gateb + (size_t)r * DIN;
  float hg[16];
  float ss = 0.f;
#pragma unroll
  for (int j = 0; j < 16; j++) {
    const int d = tid + 256 * j;
    const float g = __bfloat162float(__builtin_bit_cast(__hip_bfloat16, gr[d]));
    const float v = yr[d] * (g / (1.f + __expf(-g)));
    hg[j] = v;
    ss += v * v;
  }
#pragma unroll
  for (int o = 32; o > 0; o >>= 1) ss += __shfl_down(ss, o);
  __shared__ float red[4];
  if ((tid & 63) == 0) red[tid >> 6] = ss;
  __syncthreads();
  const float tot = red[0] + red[1] + red[2] + red[3];
  const float scale = rsqrtf(tot / (float)DIN + 1e-5f);
#pragma unroll
  for (int j = 0; j < 16; j++) {
    const int d = tid + 256 * j;
    hgb[(size_t)r * DIN + d] = f2bu(hg[j] * scale * nw[d]);
  }
}

extern "C" void kernel_launch(void* const* d_in, const int* in_sizes, int n_in,
                              void* d_out, int out_size, void* d_ws, size_t ws_size,
                              hipStream_t stream) {
  const float* hidden = (const float*)d_in[0];
  const float* w1 = (const float*)d_in[1];
  const float* cw = (const float*)d_in[2];
  const float* cb = (const float*)d_in[3];
  const float* dtb = (const float*)d_in[4];
  const float* alog = (const float*)d_in[5];
  const float* Dp = (const float*)d_in[6];
  const float* nw = (const float*)d_in[7];
  const float* w2 = (const float*)d_in[8];
  float* out = (float*)d_out;
  char* ws = (char*)d_ws;

  // Lifetime-aliased layout. R8 bug: W2B aliased GATEB while being written in
  // S1 -> GEMM1 clobbered it. Fix: W2B gets a DEDICATED region (245.4M..262M).
  const size_t OFF_GATEB = 0;            // bf16 4096x4096   S1-S4
  const size_t OFF_XBC = 33554432;       // f32 4096x4352    S2-S3
  const size_t OFF_DTV = 104857600;      // f32 4096x64      S2-S3
  const size_t OFF_DAC = 105906176;      // f32 4096x64      S2-S3
  const size_t OFF_CB = 106954752;       // f32 16x256x256   S3
  const size_t OFF_Y = 111149056;        // f32 4096x4096    S3-S4
  const size_t OFF_ST = 178257920;       // f32 1024x64x128  S3
  const size_t OFF_PV = 211812352;       // bf16 1024x64x128 S3
  const size_t OFF_PROJX = 111149056;    // f32 4096x4416    S1-S2 (aliases Y+ST head)
  const size_t OFF_HB = 183500800;       // bf16 4096x2048   S1 (aliases ST tail)
  const size_t OFF_W1B = 200278016;      // bf16 8704x2048   S1 (aliases ST tail+PV)
  const size_t OFF_W2B = 245366784;      // bf16 2048x4096   S1-S5 DEDICATED
  const size_t OFF_HGB = 33554432;       // bf16 4096x4096   S4-S5 (aliases XBC)
  const size_t NEED = 262144000;
  if (ws_size < NEED) {
    fprintf(stderr, "WS TOO SMALL: %zu < %zu\n", ws_size, NEED);
    return;
  }
  unsigned short* gateb = (unsigned short*)(ws + OFF_GATEB);
  float* xbc = (float*)(ws + OFF_XBC);
  float* dtv = (float*)(ws + OFF_DTV);
  float* dac = (float*)(ws + OFF_DAC);
  float* cbuf = (float*)(ws + OFF_CB);
  float* y = (float*)(ws + OFF_Y);
  float* st = (float*)(ws + OFF_ST);
  unsigned short* pv = (unsigned short*)(ws + OFF_PV);
  float* projx = (float*)(ws + OFF_PROJX);
  unsigned short* hb = (unsigned short*)(ws + OFF_HB);
  unsigned short* w1b = (unsigned short*)(ws + OFF_W1B);
  unsigned short* w2b = (unsigned short*)(ws + OFF_W2B);
  unsigned short* hgb = (unsigned short*)(ws + OFF_HGB);

  // S1: fused vectorized casts (hb + w1b-with-pad + w2b), then GEMM1
  k_cast3<<<4096, 256, 0, stream>>>(hidden, hb, (long)BL * DMODEL,
                                    w1, w1b, (long)PROJD * DMODEL,
                                    (long)PROJ_PAD2 * DMODEL,
                                    w2, w2b, (long)DMODEL * DIN);
  k_gemm256<true><<<dim3(PROJ_PAD2 / 256, BL / 256), 512, 0, stream>>>(
      hb, w1b, nullptr, gateb, projx, PROJD, DMODEL);
  // S2
  k_conv_silu<<<dim3(17, BL), 256, 0, stream>>>(projx, cw, cb, xbc);
  k_dt<<<16, 256, 0, stream>>>(projx, dtb, alog, dtv, dac);
  // S3
  k_cb<<<dim3(4, 16), 256, 0, stream>>>(xbc, cbuf);
  k_diag<<<dim3(NH, NCH, BB), 256, 0, stream>>>(xbc, dtv, dac, cbuf, y, st);
  k_scan<<<dim3(NH, BB), 256, 0, stream>>>(st, dac, pv);
  k_off<<<dim3(NH, NCH * 2, BB), 256, 0, stream>>>(xbc, dac, pv, Dp, y);
  // S4
  k_gatenorm<<<BL, 256, 0, stream>>>(y, gateb, nw, hgb);
  // S5
  k_gemm_bt<<<dim3(DMODEL / 128, BL / 128), 256, 0, stream>>>(
      hgb, w2b, out, DMODEL, DIN);
}

// Round 11
// 551.437 us; speedup vs baseline: 1.4751x; 1.1437x over previous
//
#include <hip/hip_runtime.h>
#include <hip/hip_bf16.h>
#include <cstdio>

#define LQ 2048      // L
#define BB 2         // batch
#define BL 4096      // B*L rows
#define DMODEL 2048
#define DIN 4096
#define NH 64
#define HD 64
#define NST 128
#define CONVD 4352
#define PROJD 8512
#define PROJ_PAD2 8704   // pad to 256 multiple for 256-tile GEMM1
#define PXW 4416     // projx width: CONVD + NH
#define CHK 256
#define NCH 8        // chunks per batch

typedef __attribute__((ext_vector_type(8))) short short8;
typedef __attribute__((ext_vector_type(4))) float f32x4;

__device__ __forceinline__ unsigned short f2bu(float x) {
  __hip_bfloat16 h = __float2bfloat16(x);
  return __builtin_bit_cast(unsigned short, h);
}

__device__ __forceinline__ float b2f(unsigned short u) {
  return __bfloat162float(__builtin_bit_cast(__hip_bfloat16, u));
}

__device__ __forceinline__ f32x4 mfma16(short8 a, short8 b, f32x4 c) {
  return __builtin_amdgcn_mfma_f32_16x16x32_bf16(a, b, c, 0, 0, 0);
}

#define GLD16(gptr, lptr)                                                  \
  __builtin_amdgcn_global_load_lds(                                        \
      (const __attribute__((address_space(1))) void*)(gptr),               \
      (__attribute__((address_space(3))) void*)(lptr), 16, 0, 0)

// ------- fused vectorized cast fp32 -> bf16 for hb / w1b(+pad) / w2b --------
__global__ void k_cast3(const float* __restrict__ s0, unsigned short* __restrict__ d0,
                        long n0,
                        const float* __restrict__ s1, unsigned short* __restrict__ d1,
                        long n1r, long n1t,
                        const float* __restrict__ s2, unsigned short* __restrict__ d2,
                        long n2) {
  const long ntot8 = (n0 + n1t + n2) >> 3;
  long i = (long)blockIdx.x * blockDim.x + threadIdx.x;
  const long stride = (long)gridDim.x * blockDim.x;
  for (; i < ntot8; i += stride) {
    const long e = i << 3;
    const float* src;
    unsigned short* dst;
    long rel, nreal;
    if (e < n0) { src = s0; dst = d0; rel = e; nreal = n0; }
    else if (e < n0 + n1t) { src = s1; dst = d1; rel = e - n0; nreal = n1r; }
    else { src = s2; dst = d2; rel = e - n0 - n1t; nreal = n2; }
    short8 pk;
    if (rel + 8 <= nreal) {
      const f32x4* sp = reinterpret_cast<const f32x4*>(src + rel);
      f32x4 v0 = sp[0], v1 = sp[1];
#pragma unroll
      for (int u = 0; u < 4; u++) {
        pk[u] = (short)f2bu(v0[u]);
        pk[4 + u] = (short)f2bu(v1[u]);
      }
    } else {
#pragma unroll
      for (int u = 0; u < 8; u++)
        pk[u] = (rel + u < nreal) ? (short)f2bu(src[rel + u]) : (short)0;
    }
    *reinterpret_cast<short8*>(dst + rel) = pk;
  }
}

// swizzled fragment read from a [256][64] bf16 LDS tile (involution: cg ^= row&7)
__device__ __forceinline__ short8 rdfrag(const unsigned short (*mp)[64], int rowbase,
                                         int lane, int kh) {
  const int row = rowbase + (lane & 15);
  const int cg = (((kh << 2) + (lane >> 4)) ^ (lane & 7)) << 3;
  return *reinterpret_cast<const short8*>(&mp[row][cg]);
}

// ==== 256x256 8-phase GEMM (R5 proven: 781 TF measured) ====================
template <bool SPLIT>
__global__ __launch_bounds__(512) void k_gemm256(
    const unsigned short* __restrict__ A, const unsigned short* __restrict__ Bw,
    float* __restrict__ C, unsigned short* __restrict__ gateb,
    float* __restrict__ projx, int Nreal, int K) {
  __shared__ unsigned short sh[2][2][256][64];  // [buf][A/B][row][col]
  const int tid = threadIdx.x;
  const int lane = tid & 63, w = tid >> 6;
  const int wm = w >> 2, wn2 = w & 3;
  const int gx = gridDim.x;
  const int nwg = gx * gridDim.y;
  const int bid = blockIdx.y * gx + blockIdx.x;
  const int qq = nwg >> 3;
  const int swz = (bid & 7) * qq + (bid >> 3);
  const int m0 = (swz / gx) * 256, n0 = (swz % gx) * 256;
  const int srow = tid >> 3;
  const int sdst = (tid & 7) * 8;                       // linear LDS col
  const int ssrc = ((tid & 7) ^ ((tid >> 3) & 7)) * 8;  // swizzled gmem col
  const unsigned short* Ab = A + (size_t)m0 * K;
  const unsigned short* Bb = Bw + (size_t)n0 * K;

#define ST(bf, mt, MP, r0, kk)                                             \
  GLD16(MP + (size_t)((r0) + srow) * K + (kk) + ssrc,                      \
        &sh[bf][mt][(r0) + srow][sdst])

  f32x4 acc[8][4] = {};
  const int nt = K >> 6;

  // prologue: stage tile 0 fully, in canonical round order
  ST(0, 0, Ab, 0, 0);   ST(0, 0, Ab, 128, 0);
  ST(0, 1, Bb, 0, 0);   ST(0, 1, Bb, 64, 0);
  ST(0, 1, Bb, 128, 0); ST(0, 1, Bb, 192, 0);
  ST(0, 0, Ab, 64, 0);  ST(0, 0, Ab, 192, 0);

#define DO_PHASE(P)                                                        \
  {                                                                        \
    const int rb = wm * 128 + (P) * 32;                                    \
    short8 a00 = rdfrag(sh[cur][0], rb, lane, 0);                          \
    short8 a01 = rdfrag(sh[cur][0], rb, lane, 1);                          \
    short8 a10 = rdfrag(sh[cur][0], rb + 16, lane, 0);                     \
    short8 a11 = rdfrag(sh[cur][0], rb + 16, lane, 1);                     \
    __builtin_amdgcn_s_setprio(1);                                         \
    _Pragma("unroll")                                                      \
    for (int nf = 0; nf < 4; nf++) {                                       \
      acc[2 * (P)][nf] = mfma16(a00, bfr[nf][0], acc[2 * (P)][nf]);        \
      acc[2 * (P)][nf] = mfma16(a01, bfr[nf][1], acc[2 * (P)][nf]);        \
      acc[2 * (P) + 1][nf] = mfma16(a10, bfr[nf][0], acc[2 * (P) + 1][nf]);\
      acc[2 * (P) + 1][nf] = mfma16(a11, bfr[nf][1], acc[2 * (P) + 1][nf]);\
    }                                                                      \
    __builtin_amdgcn_s_setprio(0);                                         \
  }

  for (int t = 0; t < nt; ++t) {
    const int cur = t & 1, nxt = cur ^ 1;
    const int kbn = (t + 1) << 6;
    const bool more = (t + 1 < nt);
    // entry: tile t rounds 0..5 (A0,A2,B0..B3) landed globally
    asm volatile("s_waitcnt vmcnt(2)" ::: "memory");
    __builtin_amdgcn_s_barrier();
    // ---- phase 0: stage A0,A2 of t+1; read all B frags + A mf0,1
    if (more) { ST(nxt, 0, Ab, 0, kbn); ST(nxt, 0, Ab, 128, kbn); }
    short8 bfr[4][2];
#pragma unroll
    for (int nf = 0; nf < 4; nf++) {
      bfr[nf][0] = rdfrag(sh[cur][1], wn2 * 64 + nf * 16, lane, 0);
      bfr[nf][1] = rdfrag(sh[cur][1], wn2 * 64 + nf * 16, lane, 1);
    }
    DO_PHASE(0)
    __builtin_amdgcn_s_barrier();
    // ---- phase 1: stage B0,B1 of t+1; A mf2,3
    if (more) { ST(nxt, 1, Bb, 0, kbn); ST(nxt, 1, Bb, 64, kbn); }
    DO_PHASE(1)
    // mid wait: tile t rounds A1,A3 landed globally
    if (more) asm volatile("s_waitcnt vmcnt(4)" ::: "memory");
    else      asm volatile("s_waitcnt vmcnt(0)" ::: "memory");
    __builtin_amdgcn_s_barrier();
    // ---- phase 2: stage B2,B3 of t+1; A mf4,5
    if (more) { ST(nxt, 1, Bb, 128, kbn); ST(nxt, 1, Bb, 192, kbn); }
    DO_PHASE(2)
    __builtin_amdgcn_s_barrier();
    // ---- phase 3: stage A1,A3 of t+1; A mf6,7
    if (more) { ST(nxt, 0, Ab, 64, kbn); ST(nxt, 0, Ab, 192, kbn); }
    DO_PHASE(3)
    // no trailing barrier: next tile's entry vmcnt+barrier covers it
  }
#undef DO_PHASE
#undef ST

  // epilogue
#pragma unroll
  for (int mf = 0; mf < 8; mf++) {
    const int row = m0 + wm * 128 + mf * 16 + ((lane >> 4) << 2);
#pragma unroll
    for (int nf = 0; nf < 4; nf++) {
      const int col = n0 + wn2 * 64 + nf * 16 + (lane & 15);
      if (SPLIT) {
        if (col < DIN) {
#pragma unroll
          for (int v = 0; v < 4; v++)
            gateb[(size_t)(row + v) * DIN + col] = f2bu(acc[mf][nf][v]);
        } else if (col < PROJD) {
#pragma unroll
          for (int v = 0; v < 4; v++)
            projx[(size_t)(row + v) * PXW + (col - DIN)] = acc[mf][nf][v];
        }
      } else {
        if (col < Nreal) {
#pragma unroll
          for (int v = 0; v < 4; v++)
            C[(size_t)(row + v) * Nreal + col] = acc[mf][nf][v];
        }
      }
    }
  }
}

// ---- 128x128 bf16 GEMM (R4 proven) — used for GEMM2 (512 blocks, 2 rounds) -
__global__ __launch_bounds__(256) void k_gemm_bt(
    const unsigned short* __restrict__ A, const unsigned short* __restrict__ Bw,
    float* __restrict__ C, int Nreal, int K) {
  __shared__ unsigned short lA[128][64];
  __shared__ unsigned short lB[128][64];
  const int tid = threadIdx.x;
  const int lane = tid & 63, w = tid >> 6;
  const int gx = gridDim.x;
  const int nwg = gx * gridDim.y;
  const int bid = blockIdx.y * gx + blockIdx.x;
  const int qq = nwg >> 3;
  const int swz = (bid & 7) * qq + (bid >> 3);
  const int m0 = (swz / gx) * 128, n0 = (swz % gx) * 128;
  const int wr = (w >> 1) * 64, wc = (w & 1) * 64;
  const int sr = tid >> 3;
  const int sdst = (tid & 7) * 8;
  const int ssrc = ((tid & 7) ^ ((tid >> 3) & 7)) * 8;
  f32x4 acc[4][4] = {};
  for (int kb = 0; kb < K; kb += 64) {
#pragma unroll
    for (int i = 0; i < 4; i++) {
      const int r = sr + i * 32;
      GLD16(A + (size_t)(m0 + r) * K + kb + ssrc, &lA[r][sdst]);
      GLD16(Bw + (size_t)(n0 + r) * K + kb + ssrc, &lB[r][sdst]);
    }
    __syncthreads();
#pragma unroll
    for (int kk = 0; kk < 64; kk += 32) {
      short8 af[4], bf[4];
      const int cg = ((((kk >> 3) + (lane >> 4)) ^ (lane & 7)) << 3);
#pragma unroll
      for (int i = 0; i < 4; i++) {
        af[i] = *reinterpret_cast<const short8*>(&lA[wr + i * 16 + (lane & 15)][cg]);
        bf[i] = *reinterpret_cast<const short8*>(&lB[wc + i * 16 + (lane & 15)][cg]);
      }
#pragma unroll
      for (int mi = 0; mi < 4; mi++)
#pragma unroll
        for (int ni = 0; ni < 4; ni++)
          acc[mi][ni] = mfma16(af[mi], bf[ni], acc[mi][ni]);
    }
    __syncthreads();
  }
#pragma unroll
  for (int mi = 0; mi < 4; mi++) {
    const int row = m0 + wr + mi * 16 + ((lane >> 4) << 2);
#pragma unroll
    for (int ni = 0; ni < 4; ni++) {
      const int col = n0 + wc + ni * 16 + (lane & 15);
      if (col < Nreal) {
#pragma unroll
        for (int v = 0; v < 4; v++)
          C[(size_t)(row + v) * Nreal + col] = acc[mi][ni][v];
      }
    }
  }
}

// ------- causal depthwise conv (K=4) + SiLU -> bf16 xbc ---------------------
__global__ __launch_bounds__(256) void k_conv_silu(
    const float* __restrict__ projx, const float* __restrict__ cw,
    const float* __restrict__ cb, unsigned short* __restrict__ xbc) {
  const int ch = blockIdx.x * 256 + threadIdx.x;  // 17*256 = 4352 exact
  const int bt = blockIdx.y;
  const int b = bt >> 11, t = bt & 2047;
  float acc = cb[ch];
#pragma unroll
  for (int i = 0; i < 4; i++) {
    int tt = t - 3 + i;
    if (tt >= 0)
      acc += cw[ch * 4 + i] * projx[((size_t)b * LQ + tt) * PXW + ch];
  }
  float o = acc / (1.f + __expf(-acc));
  xbc[(size_t)bt * CONVD + ch] = f2bu(o);
}

// ------- dt softplus + per-chunk cumsum(dt*A): parallel 2-phase scan --------
__global__ __launch_bounds__(256) void k_dt(
    const float* __restrict__ projx, const float* __restrict__ dtb,
    const float* __restrict__ alog, float* __restrict__ dtv,
    float* __restrict__ dac) {
  const int bc = blockIdx.x;  // 16 = b*8+c
  const int b = bc >> 3, c = bc & 7;
  const int h = threadIdx.x & 63, q = threadIdx.x >> 6;
  const float bias = dtb[h];
  const float Ah = -__expf(alog[h]);
  const size_t base = (size_t)b * LQ + c * CHK + q * 64;
  float vals[64];
  float part = 0.f;
#pragma unroll
  for (int j = 0; j < 64; j++) {
    float raw = projx[(base + j) * PXW + CONVD + h] + bias;
    float dt = raw > 20.f ? raw : log1pf(__expf(raw));
    vals[j] = dt;
    dtv[(base + j) * NH + h] = dt;
    part += dt;
  }
  __shared__ float partials[4][64];
  partials[q][h] = part;
  __syncthreads();
  float cum = 0.f;
  for (int qq = 0; qq < q; qq++) cum += partials[qq][h];
  cum *= Ah;
#pragma unroll
  for (int j = 0; j < 64; j++) {
    cum += vals[j] * Ah;
    dac[(base + j) * NH + h] = cum;
  }
}

// ---------------- CB[t][s] = sum_n C[t][n]*B[s][n] per (b,c) ----------------
__global__ __launch_bounds__(256) void k_cb(const unsigned short* __restrict__ xbc,
                                            float* __restrict__ cbuf) {
  const int q = blockIdx.x;   // 4 quadrants
  const int bc = blockIdx.y;  // 16
  const int b = bc >> 3, c = bc & 7;
  const int qt = q >> 1, qs = q & 1;
  __shared__ unsigned short lC[128][136];
  __shared__ unsigned short lB[128][136];
  const int tid = threadIdx.x, lane = tid & 63, w = tid >> 6;
  {
    int r = tid >> 1, hf = tid & 1;
    size_t rowc = (size_t)b * LQ + c * CHK + qt * 128 + r;
    size_t rowb = (size_t)b * LQ + c * CHK + qs * 128 + r;
    const unsigned short* crp = xbc + rowc * CONVD + DIN + NST + hf * 64;
    const unsigned short* brp = xbc + rowb * CONVD + DIN + hf * 64;
#pragma unroll
    for (int n8 = 0; n8 < 8; n8++) {
      *reinterpret_cast<short8*>(&lC[r][hf * 64 + n8 * 8]) =
          *reinterpret_cast<const short8*>(crp + n8 * 8);
      *reinterpret_cast<short8*>(&lB[r][hf * 64 + n8 * 8]) =
          *reinterpret_cast<const short8*>(brp + n8 * 8);
    }
  }
  __syncthreads();
  const int wr = (w >> 1) * 64, wc = (w & 1) * 64;
  f32x4 acc[4][4] = {};
#pragma unroll
  for (int kk = 0; kk < 128; kk += 32) {
    short8 a[4], bb[4];
    const int ko = kk + ((lane >> 4) << 3);
#pragma unroll
    for (int i = 0; i < 4; i++) {
      a[i] = *reinterpret_cast<const short8*>(&lC[wr + i * 16 + (lane & 15)][ko]);
      bb[i] = *reinterpret_cast<const short8*>(&lB[wc + i * 16 + (lane & 15)][ko]);
    }
#pragma unroll
    for (int mi = 0; mi < 4; mi++)
#pragma unroll
      for (int ni = 0; ni < 4; ni++)
        acc[mi][ni] = mfma16(a[mi], bb[ni], acc[mi][ni]);
  }
  float* outp = cbuf + (size_t)bc * (CHK * CHK);
#pragma unroll
  for (int mi = 0; mi < 4; mi++) {
    const int t = qt * 128 + wr + mi * 16 + ((lane >> 4) << 2);
#pragma unroll
    for (int ni = 0; ni < 4; ni++) {
      const int s = qs * 128 + wc + ni * 16 + (lane & 15);
#pragma unroll
      for (int v = 0; v < 4; v++)
        outp[(size_t)(t + v) * CHK + s] = acc[mi][ni][v];
    }
  }
}

// ---------------- fused Y_diag + states per (b,c,h) -------------------------
// bf16 xbc. Decay: full blocks use END-pivot factorization
// exp(da_t-da_s) = exp(da_t-da_sE) * exp(da_sE-da_s), both exponents <= 0
// (da monotone decreasing, t > sE >= s) -> no overflow. Diagonal block uses
// direct per-pair exp. Fully-masked units write zeros, skip cbuf+math.
__global__ __launch_bounds__(256) void k_diag(
    const unsigned short* __restrict__ xbc, const float* __restrict__ dtv,
    const float* __restrict__ dac, const float* __restrict__ cbuf,
    float* __restrict__ y, float* __restrict__ st) {
  const int h = blockIdx.x, c = blockIdx.y, b = blockIdx.z;
  const int cs = c * CHK;
  __shared__ unsigned short lXt[64][136];   // (p, s_loc) x*dt, bf16
  __shared__ unsigned short lBt[128][136];  // (n, s_loc) B*decay, bf16
  __shared__ unsigned short lS[256][40];    // (t, s-block32) masked S, bf16
  __shared__ float lda[256];
  __shared__ float lesE[256];               // exp(lda[s|31] - lda[s]) <= 1
  const int tid = threadIdx.x, lane = tid & 63, w = tid >> 6;
  lda[tid] = dac[((size_t)b * LQ + cs + tid) * NH + h];
  __syncthreads();
  lesE[tid] = __expf(lda[tid | 31] - lda[tid]);
  const float dalast = lda[255];
  const float* cbp = cbuf + ((size_t)(b * NCH + c)) * (CHK * CHK);
  const float da_t = lda[tid];
  f32x4 accY[4][4] = {};
  f32x4 accS[4][2] = {};
  const int wn = w * 32;
  const int sl = tid & 127, sub = tid >> 7;  // 2 threads per s-value
  for (int half = 0; half < 2; half++) {
    {
      const int s = half * 128 + sl;
      const size_t row = (size_t)b * LQ + cs + s;
      const unsigned short* xrow = xbc + row * CONVD;
      const float dts = dtv[row * NH + h];
      const float dec = __expf(dalast - lda[s]);
      // x part: 32 bf16 els per (sl,sub)
#pragma unroll
      for (int g = 0; g < 4; g++) {
        short8 xv = *reinterpret_cast<const short8*>(xrow + h * HD + sub * 32 + g * 8);
#pragma unroll
        for (int u = 0; u < 8; u++)
          lXt[sub * 32 + g * 8 + u][sl] = f2bu(b2f((unsigned short)xv[u]) * dts);
      }
      // B part: 64 bf16 els per (sl,sub)
#pragma unroll
      for (int g = 0; g < 8; g++) {
        short8 bv = *reinterpret_cast<const short8*>(xrow + DIN + sub * 64 + g * 8);
#pragma unroll
        for (int u = 0; u < 8; u++)
          lBt[sub * 64 + g * 8 + u][sl] = f2bu(b2f((unsigned short)bv[u]) * dec);
      }
    }
    __syncthreads();
    for (int sb4 = 0; sb4 < 4; sb4++) {
      const int sb = half * 4 + sb4;
      {
        const int t = tid;
        const int tb = t >> 5;
        if (tb > sb) {
          // full block: end-pivot factorization, both factors <= 1
          const float et = __expf(da_t - lda[sb * 32 + 31]);
          const f32x4* cr = reinterpret_cast<const f32x4*>(cbp + (size_t)t * CHK + sb * 32);
          f32x4 vv[8];
#pragma unroll
          for (int j4 = 0; j4 < 8; j4++) vv[j4] = cr[j4];
#pragma unroll
          for (int g = 0; g < 4; g++) {
            short8 pk;
#pragma unroll
            for (int e = 0; e < 8; e++) {
              const int j = g * 8 + e;
              pk[e] = (short)f2bu(vv[j >> 2][j & 3] * et * lesE[sb * 32 + j]);
            }
            *reinterpret_cast<short8*>(&lS[t][g * 8]) = pk;
          }
        } else if (tb == sb) {
          // diagonal block: direct per-pair exp (exponent <= 0)
          const f32x4* cr = reinterpret_cast<const f32x4*>(cbp + (size_t)t * CHK + sb * 32);
          f32x4 vv[8];
#pragma unroll
          for (int j4 = 0; j4 < 8; j4++) vv[j4] = cr[j4];
          const int tl = t & 31;
#pragma unroll
          for (int g = 0; g < 4; g++) {
            short8 pk;
#pragma unroll
            for (int e = 0; e < 8; e++) {
              const int j = g * 8 + e;
              float val = (j <= tl)
                  ? vv[j >> 2][j & 3] * __expf(da_t - lda[sb * 32 + j]) : 0.f;
              pk[e] = (short)f2bu(val);
            }
            *reinterpret_cast<short8*>(&lS[t][g * 8]) = pk;
          }
        } else {
          short8 z = {};
#pragma unroll
          for (int g = 0; g < 4; g++)
            *reinterpret_cast<short8*>(&lS[tid][g * 8]) = z;
        }
      }
      __syncthreads();
      short8 sf[4], xf[4], btf[2];
      const int ko = ((lane >> 4) << 3);
      const int so = sb4 * 32 + ko;
#pragma unroll
      for (int i = 0; i < 4; i++) {
        sf[i] = *reinterpret_cast<const short8*>(&lS[w * 64 + i * 16 + (lane & 15)][ko]);
        xf[i] = *reinterpret_cast<const short8*>(&lXt[i * 16 + (lane & 15)][so]);
      }
#pragma unroll
      for (int i = 0; i < 2; i++)
        btf[i] = *reinterpret_cast<const short8*>(&lBt[wn + i * 16 + (lane & 15)][so]);
#pragma unroll
      for (int mi = 0; mi < 4; mi++)
#pragma unroll
        for (int ni = 0; ni < 4; ni++)
          accY[mi][ni] = mfma16(sf[mi], xf[ni], accY[mi][ni]);
#pragma unroll
      for (int mi = 0; mi < 4; mi++)
#pragma unroll
        for (int nj = 0; nj < 2; nj++)
          accS[mi][nj] = mfma16(xf[mi], btf[nj], accS[mi][nj]);
      __syncthreads();
    }
  }
#pragma unroll
  for (int mi = 0; mi < 4; mi++) {
    const int t = w * 64 + mi * 16 + ((lane >> 4) << 2);
#pragma unroll
    for (int ni = 0; ni < 4; ni++) {
      const int p = ni * 16 + (lane & 15);
#pragma unroll
      for (int v = 0; v < 4; v++)
        y[((size_t)b * LQ + cs + t + v) * DIN + h * HD + p] = accY[mi][ni][v];
    }
  }
  float* stp = st + ((size_t)((b * NCH + c) * NH + h)) * (HD * NST);
#pragma unroll
  for (int mi = 0; mi < 4; mi++) {
    const int p = mi * 16 + ((lane >> 4) << 2);
#pragma unroll
    for (int nj = 0; nj < 2; nj++) {
      const int n = wn + nj * 16 + (lane & 15);
#pragma unroll
      for (int v = 0; v < 4; v++)
        stp[(size_t)(p + v) * NST + n] = accS[mi][nj][v];
    }
  }
}

// ---------------- inter-chunk state scan (pv stored as bf16) ----------------
__global__ void k_scan(const float* __restrict__ st, const float* __restrict__ dac,
                       unsigned short* __restrict__ pv) {
  const int h = blockIdx.x, b = blockIdx.y;
  const int tid = threadIdx.x;
  float P[32];
#pragma unroll
  for (int j = 0; j < 32; j++) P[j] = 0.f;
  for (int c = 0; c < NCH; c++) {
    const size_t base = ((size_t)((b * NCH + c) * NH + h)) * (HD * NST);
#pragma unroll
    for (int j = 0; j < 32; j++) pv[base + tid + 256 * j] = f2bu(P[j]);
    const float d = __expf(dac[((size_t)b * LQ + c * CHK + 255) * NH + h]);
#pragma unroll
    for (int j = 0; j < 32; j++) P[j] = P[j] * d + st[base + tid + 256 * j];
  }
}

// ---------------- Y_off + D*x accumulate into y -----------------------------
// t-extent 128 per block (grid y = c*2 + th) -> 3 blocks/CU. bf16 xbc copies.
__global__ __launch_bounds__(256) void k_off(
    const unsigned short* __restrict__ xbc, const float* __restrict__ dac,
    const unsigned short* __restrict__ pv, const float* __restrict__ Dp,
    float* __restrict__ y) {
  const int h = blockIdx.x;
  const int cth = blockIdx.y;
  const int c = cth >> 1, th = cth & 1;
  const int b = blockIdx.z;
  const int cs = c * CHK, t0 = th * 128;
  __shared__ unsigned short lC[128][136];  // (t_loc, n)
  __shared__ unsigned short lP[64][136];   // (p, n)
  __shared__ float lda[128];
  const int tid = threadIdx.x, lane = tid & 63, w = tid >> 6;
  const int wt = w >> 1, wp = w & 1;
  {
    const int r = tid >> 1, hf = tid & 1;
    const size_t row = (size_t)b * LQ + cs + t0 + r;
    if (hf == 0) lda[r] = dac[row * NH + h];
    const unsigned short* cr = xbc + row * CONVD + DIN + NST + hf * 64;
#pragma unroll
    for (int n8 = 0; n8 < 8; n8++)
      *reinterpret_cast<short8*>(&lC[r][hf * 64 + n8 * 8]) =
          *reinterpret_cast<const short8*>(cr + n8 * 8);
  }
  if (tid < 64) {
    const unsigned short* pr =
        pv + ((size_t)((b * NCH + c) * NH + h)) * (HD * NST) + (size_t)tid * NST;
#pragma unroll
    for (int n8 = 0; n8 < 16; n8++)
      *reinterpret_cast<short8*>(&lP[tid][n8 * 8]) =
          *reinterpret_cast<const short8*>(pr + n8 * 8);
  }
  __syncthreads();
  f32x4 acc[4][2] = {};
#pragma unroll
  for (int kk = 0; kk < 128; kk += 32) {
    short8 a[4], bb[2];
    const int ko = kk + ((lane >> 4) << 3);
#pragma unroll
    for (int i = 0; i < 4; i++)
      a[i] = *reinterpret_cast<const short8*>(&lC[wt * 64 + i * 16 + (lane & 15)][ko]);
#pragma unroll
    for (int j = 0; j < 2; j++)
      bb[j] = *reinterpret_cast<const short8*>(&lP[wp * 32 + j * 16 + (lane & 15)][ko]);
#pragma unroll
    for (int mi = 0; mi < 4; mi++)
#pragma unroll
      for (int nj = 0; nj < 2; nj++)
        acc[mi][nj] = mfma16(a[mi], bb[nj], acc[mi][nj]);
  }
  const float Dh = Dp[h];
#pragma unroll
  for (int mi = 0; mi < 4; mi++) {
    const int tl = wt * 64 + mi * 16 + ((lane >> 4) << 2);
#pragma unroll
    for (int nj = 0; nj < 2; nj++) {
      const int p = wp * 32 + nj * 16 + (lane & 15);
#pragma unroll
      for (int v = 0; v < 4; v++) {
        const int tt = tl + v;
        const size_t row = (size_t)b * LQ + cs + t0 + tt;
        const float scale = __expf(lda[tt]);
        const float xval = b2f(xbc[row * CONVD + h * HD + p]);
        const size_t yi = row * DIN + h * HD + p;
        y[yi] += scale * acc[mi][nj][v] + Dh * xval;
      }
    }
  }
}

// ---------------- gate*silu + RMSNorm -> bf16 -------------------------------
__global__ __launch_bounds__(256) void k_gatenorm(
    const float* __restrict__ y, const unsigned short* __restrict__ gateb,
    const float* __restrict__ nw, unsigned short* __restrict__ hgb) {
  const int r = blockIdx.x;
  const int tid = threadIdx.x;
  const float* yr = y + (size_t)r * DIN;
  const unsigned short* gr = gateb + (size_t)r * DIN;
  float hg[16];
  float ss = 0.f;
#pragma unroll
  for (int j = 0; j < 16; j++) {
    const int d = tid + 256 * j;
    const float g = b2f(gr[d]);
    const float v = yr[d] * (g / (1.f + __expf(-g)));
    hg[j] = v;
    ss += v * v;
  }
#pragma unroll
  for (int o = 32; o > 0; o >>= 1) ss += __shfl_down(ss, o);
  __shared__ float red[4];
  if ((tid & 63) == 0) red[tid >> 6] = ss;
  __syncthreads();
  const float tot = red[0] + red[1] + red[2] + red[3];
  const float scale = rsqrtf(tot / (float)DIN + 1e-5f);
#pragma unroll
  for (int j = 0; j < 16; j++) {
    const int d = tid + 256 * j;
    hgb[(size_t)r * DIN + d] = f2bu(hg[j] * scale * nw[d]);
  }
}

extern "C" void kernel_launch(void* const* d_in, const int* in_sizes, int n_in,
                              void* d_out, int out_size, void* d_ws, size_t ws_size,
                              hipStream_t stream) {
  const float* hidden = (const float*)d_in[0];
  const float* w1 = (const float*)d_in[1];
  const float* cw = (const float*)d_in[2];
  const float* cb = (const float*)d_in[3];
  const float* dtb = (const float*)d_in[4];
  const float* alog = (const float*)d_in[5];
  const float* Dp = (const float*)d_in[6];
  const float* nw = (const float*)d_in[7];
  const float* w2 = (const float*)d_in[8];
  float* out = (float*)d_out;
  char* ws = (char*)d_ws;

  // Lifetime-aliased layout. W2B has a DEDICATED region (written in S1, read S5).
  const size_t OFF_GATEB = 0;            // bf16 4096x4096   S1-S4
  const size_t OFF_XBC = 33554432;       // bf16 4096x4352   S2-S3
  const size_t OFF_DTV = 104857600;      // f32 4096x64      S2-S3
  const size_t OFF_DAC = 105906176;      // f32 4096x64      S2-S3
  const size_t OFF_CB = 106954752;       // f32 16x256x256   S3
  const size_t OFF_Y = 111149056;        // f32 4096x4096    S3-S4
  const size_t OFF_ST = 178257920;       // f32 1024x64x128  S3
  const size_t OFF_PV = 211812352;       // bf16 1024x64x128 S3
  const size_t OFF_PROJX = 111149056;    // f32 4096x4416    S1-S2 (aliases Y+ST head)
  const size_t OFF_HB = 183500800;       // bf16 4096x2048   S1 (aliases ST tail)
  const size_t OFF_W1B = 200278016;      // bf16 8704x2048   S1 (aliases ST tail+PV)
  const size_t OFF_W2B = 245366784;      // bf16 2048x4096   S1-S5 DEDICATED
  const size_t OFF_HGB = 33554432;       // bf16 4096x4096   S4-S5 (aliases XBC)
  const size_t NEED = 262144000;
  if (ws_size < NEED) {
    fprintf(stderr, "WS TOO SMALL: %zu < %zu\n", ws_size, NEED);
    return;
  }
  unsigned short* gateb = (unsigned short*)(ws + OFF_GATEB);
  unsigned short* xbc = (unsigned short*)(ws + OFF_XBC);
  float* dtv = (float*)(ws + OFF_DTV);
  float* dac = (float*)(ws + OFF_DAC);
  float* cbuf = (float*)(ws + OFF_CB);
  float* y = (float*)(ws + OFF_Y);
  float* st = (float*)(ws + OFF_ST);
  unsigned short* pv = (unsigned short*)(ws + OFF_PV);
  float* projx = (float*)(ws + OFF_PROJX);
  unsigned short* hb = (unsigned short*)(ws + OFF_HB);
  unsigned short* w1b = (unsigned short*)(ws + OFF_W1B);
  unsigned short* w2b = (unsigned short*)(ws + OFF_W2B);
  unsigned short* hgb = (unsigned short*)(ws + OFF_HGB);

  // S1: fused vectorized casts (hb + w1b-with-pad + w2b), then GEMM1
  k_cast3<<<4096, 256, 0, stream>>>(hidden, hb, (long)BL * DMODEL,
                                    w1, w1b, (long)PROJD * DMODEL,
                                    (long)PROJ_PAD2 * DMODEL,
                                    w2, w2b, (long)DMODEL * DIN);
  k_gemm256<true><<<dim3(PROJ_PAD2 / 256, BL / 256), 512, 0, stream>>>(
      hb, w1b, nullptr, gateb, projx, PROJD, DMODEL);
  // S2
  k_conv_silu<<<dim3(17, BL), 256, 0, stream>>>(projx, cw, cb, xbc);
  k_dt<<<16, 256, 0, stream>>>(projx, dtb, alog, dtv, dac);
  // S3
  k_cb<<<dim3(4, 16), 256, 0, stream>>>(xbc, cbuf);
  k_diag<<<dim3(NH, NCH, BB), 256, 0, stream>>>(xbc, dtv, dac, cbuf, y, st);
  k_scan<<<dim3(NH, BB), 256, 0, stream>>>(st, dac, pv);
  k_off<<<dim3(NH, NCH * 2, BB), 256, 0, stream>>>(xbc, dac, pv, Dp, y);
  // S4
  k_gatenorm<<<BL, 256, 0, stream>>>(y, gateb, nw, hgb);
  // S5
  k_gemm_bt<<<dim3(DMODEL / 128, BL / 128), 256, 0, stream>>>(
      hgb, w2b, out, DMODEL, DIN);
}

// Round 12
// 550.112 us; speedup vs baseline: 1.4787x; 1.0024x over previous
//
#include <hip/hip_runtime.h>
#include <hip/hip_bf16.h>
#include <cstdio>

#define LQ 2048      // L
#define BB 2         // batch
#define BL 4096      // B*L rows
#define DMODEL 2048
#define DIN 4096
#define NH 64
#define HD 64
#define NST 128
#define CONVD 4352
#define PROJD 8512
#define PROJ_PAD2 8704   // pad to 256 multiple for 256-tile GEMM1
#define PXW 4416     // projx width: CONVD + NH
#define CHK 256
#define NCH 8        // chunks per batch

typedef __attribute__((ext_vector_type(8))) short short8;
typedef __attribute__((ext_vector_type(4))) float f32x4;

__device__ __forceinline__ unsigned short f2bu(float x) {
  __hip_bfloat16 h = __float2bfloat16(x);
  return __builtin_bit_cast(unsigned short, h);
}

__device__ __forceinline__ float b2f(unsigned short u) {
  return __bfloat162float(__builtin_bit_cast(__hip_bfloat16, u));
}

__device__ __forceinline__ f32x4 mfma16(short8 a, short8 b, f32x4 c) {
  return __builtin_amdgcn_mfma_f32_16x16x32_bf16(a, b, c, 0, 0, 0);
}

#define GLD16(gptr, lptr)                                                  \
  __builtin_amdgcn_global_load_lds(                                        \
      (const __attribute__((address_space(1))) void*)(gptr),               \
      (__attribute__((address_space(3))) void*)(lptr), 16, 0, 0)

// ------- fused vectorized cast fp32 -> bf16 for hb / w1b(+pad) / w2b --------
__global__ void k_cast3(const float* __restrict__ s0, unsigned short* __restrict__ d0,
                        long n0,
                        const float* __restrict__ s1, unsigned short* __restrict__ d1,
                        long n1r, long n1t,
                        const float* __restrict__ s2, unsigned short* __restrict__ d2,
                        long n2) {
  const long ntot8 = (n0 + n1t + n2) >> 3;
  long i = (long)blockIdx.x * blockDim.x + threadIdx.x;
  const long stride = (long)gridDim.x * blockDim.x;
  for (; i < ntot8; i += stride) {
    const long e = i << 3;
    const float* src;
    unsigned short* dst;
    long rel, nreal;
    if (e < n0) { src = s0; dst = d0; rel = e; nreal = n0; }
    else if (e < n0 + n1t) { src = s1; dst = d1; rel = e - n0; nreal = n1r; }
    else { src = s2; dst = d2; rel = e - n0 - n1t; nreal = n2; }
    short8 pk;
    if (rel + 8 <= nreal) {
      const f32x4* sp = reinterpret_cast<const f32x4*>(src + rel);
      f32x4 v0 = sp[0], v1 = sp[1];
#pragma unroll
      for (int u = 0; u < 4; u++) {
        pk[u] = (short)f2bu(v0[u]);
        pk[4 + u] = (short)f2bu(v1[u]);
      }
    } else {
#pragma unroll
      for (int u = 0; u < 8; u++)
        pk[u] = (rel + u < nreal) ? (short)f2bu(src[rel + u]) : (short)0;
    }
    *reinterpret_cast<short8*>(dst + rel) = pk;
  }
}

// swizzled fragment read from a [256][64] bf16 LDS tile (involution: cg ^= row&7)
__device__ __forceinline__ short8 rdfrag(const unsigned short (*mp)[64], int rowbase,
                                         int lane, int kh) {
  const int row = rowbase + (lane & 15);
  const int cg = (((kh << 2) + (lane >> 4)) ^ (lane & 7)) << 3;
  return *reinterpret_cast<const short8*>(&mp[row][cg]);
}

// ==== 256x256 8-phase GEMM (R5 proven: 781 TF measured) ====================
template <bool SPLIT>
__global__ __launch_bounds__(512) void k_gemm256(
    const unsigned short* __restrict__ A, const unsigned short* __restrict__ Bw,
    float* __restrict__ C, unsigned short* __restrict__ gateb,
    float* __restrict__ projx, int Nreal, int K) {
  __shared__ unsigned short sh[2][2][256][64];  // [buf][A/B][row][col]
  const int tid = threadIdx.x;
  const int lane = tid & 63, w = tid >> 6;
  const int wm = w >> 2, wn2 = w & 3;
  const int gx = gridDim.x;
  const int nwg = gx * gridDim.y;
  const int bid = blockIdx.y * gx + blockIdx.x;
  const int qq = nwg >> 3;
  const int swz = (bid & 7) * qq + (bid >> 3);
  const int m0 = (swz / gx) * 256, n0 = (swz % gx) * 256;
  const int srow = tid >> 3;
  const int sdst = (tid & 7) * 8;                       // linear LDS col
  const int ssrc = ((tid & 7) ^ ((tid >> 3) & 7)) * 8;  // swizzled gmem col
  const unsigned short* Ab = A + (size_t)m0 * K;
  const unsigned short* Bb = Bw + (size_t)n0 * K;

#define ST(bf, mt, MP, r0, kk)                                             \
  GLD16(MP + (size_t)((r0) + srow) * K + (kk) + ssrc,                      \
        &sh[bf][mt][(r0) + srow][sdst])

  f32x4 acc[8][4] = {};
  const int nt = K >> 6;

  // prologue: stage tile 0 fully, in canonical round order
  ST(0, 0, Ab, 0, 0);   ST(0, 0, Ab, 128, 0);
  ST(0, 1, Bb, 0, 0);   ST(0, 1, Bb, 64, 0);
  ST(0, 1, Bb, 128, 0); ST(0, 1, Bb, 192, 0);
  ST(0, 0, Ab, 64, 0);  ST(0, 0, Ab, 192, 0);

#define DO_PHASE(P)                                                        \
  {                                                                        \
    const int rb = wm * 128 + (P) * 32;                                    \
    short8 a00 = rdfrag(sh[cur][0], rb, lane, 0);                          \
    short8 a01 = rdfrag(sh[cur][0], rb, lane, 1);                          \
    short8 a10 = rdfrag(sh[cur][0], rb + 16, lane, 0);                     \
    short8 a11 = rdfrag(sh[cur][0], rb + 16, lane, 1);                     \
    __builtin_amdgcn_s_setprio(1);                                         \
    _Pragma("unroll")                                                      \
    for (int nf = 0; nf < 4; nf++) {                                       \
      acc[2 * (P)][nf] = mfma16(a00, bfr[nf][0], acc[2 * (P)][nf]);        \
      acc[2 * (P)][nf] = mfma16(a01, bfr[nf][1], acc[2 * (P)][nf]);        \
      acc[2 * (P) + 1][nf] = mfma16(a10, bfr[nf][0], acc[2 * (P) + 1][nf]);\
      acc[2 * (P) + 1][nf] = mfma16(a11, bfr[nf][1], acc[2 * (P) + 1][nf]);\
    }                                                                      \
    __builtin_amdgcn_s_setprio(0);                                         \
  }

  for (int t = 0; t < nt; ++t) {
    const int cur = t & 1, nxt = cur ^ 1;
    const int kbn = (t + 1) << 6;
    const bool more = (t + 1 < nt);
    // entry: tile t rounds 0..5 (A0,A2,B0..B3) landed globally
    asm volatile("s_waitcnt vmcnt(2)" ::: "memory");
    __builtin_amdgcn_s_barrier();
    // ---- phase 0: stage A0,A2 of t+1; read all B frags + A mf0,1
    if (more) { ST(nxt, 0, Ab, 0, kbn); ST(nxt, 0, Ab, 128, kbn); }
    short8 bfr[4][2];
#pragma unroll
    for (int nf = 0; nf < 4; nf++) {
      bfr[nf][0] = rdfrag(sh[cur][1], wn2 * 64 + nf * 16, lane, 0);
      bfr[nf][1] = rdfrag(sh[cur][1], wn2 * 64 + nf * 16, lane, 1);
    }
    DO_PHASE(0)
    __builtin_amdgcn_s_barrier();
    // ---- phase 1: stage B0,B1 of t+1; A mf2,3
    if (more) { ST(nxt, 1, Bb, 0, kbn); ST(nxt, 1, Bb, 64, kbn); }
    DO_PHASE(1)
    // mid wait: tile t rounds A1,A3 landed globally
    if (more) asm volatile("s_waitcnt vmcnt(4)" ::: "memory");
    else      asm volatile("s_waitcnt vmcnt(0)" ::: "memory");
    __builtin_amdgcn_s_barrier();
    // ---- phase 2: stage B2,B3 of t+1; A mf4,5
    if (more) { ST(nxt, 1, Bb, 128, kbn); ST(nxt, 1, Bb, 192, kbn); }
    DO_PHASE(2)
    __builtin_amdgcn_s_barrier();
    // ---- phase 3: stage A1,A3 of t+1; A mf6,7
    if (more) { ST(nxt, 0, Ab, 64, kbn); ST(nxt, 0, Ab, 192, kbn); }
    DO_PHASE(3)
    // no trailing barrier: next tile's entry vmcnt+barrier covers it
  }
#undef DO_PHASE
#undef ST

  // epilogue
#pragma unroll
  for (int mf = 0; mf < 8; mf++) {
    const int row = m0 + wm * 128 + mf * 16 + ((lane >> 4) << 2);
#pragma unroll
    for (int nf = 0; nf < 4; nf++) {
      const int col = n0 + wn2 * 64 + nf * 16 + (lane & 15);
      if (SPLIT) {
        if (col < DIN) {
#pragma unroll
          for (int v = 0; v < 4; v++)
            gateb[(size_t)(row + v) * DIN + col] = f2bu(acc[mf][nf][v]);
        } else if (col < PROJD) {
#pragma unroll
          for (int v = 0; v < 4; v++)
            projx[(size_t)(row + v) * PXW + (col - DIN)] = acc[mf][nf][v];
        }
      } else {
        if (col < Nreal) {
#pragma unroll
          for (int v = 0; v < 4; v++)
            C[(size_t)(row + v) * Nreal + col] = acc[mf][nf][v];
        }
      }
    }
  }
}

// ---- 128x128 bf16 GEMM (R4 proven) — used for GEMM2 (512 blocks, 2 rounds) -
__global__ __launch_bounds__(256) void k_gemm_bt(
    const unsigned short* __restrict__ A, const unsigned short* __restrict__ Bw,
    float* __restrict__ C, int Nreal, int K) {
  __shared__ unsigned short lA[128][64];
  __shared__ unsigned short lB[128][64];
  const int tid = threadIdx.x;
  const int lane = tid & 63, w = tid >> 6;
  const int gx = gridDim.x;
  const int nwg = gx * gridDim.y;
  const int bid = blockIdx.y * gx + blockIdx.x;
  const int qq = nwg >> 3;
  const int swz = (bid & 7) * qq + (bid >> 3);
  const int m0 = (swz / gx) * 128, n0 = (swz % gx) * 128;
  const int wr = (w >> 1) * 64, wc = (w & 1) * 64;
  const int sr = tid >> 3;
  const int sdst = (tid & 7) * 8;
  const int ssrc = ((tid & 7) ^ ((tid >> 3) & 7)) * 8;
  f32x4 acc[4][4] = {};
  for (int kb = 0; kb < K; kb += 64) {
#pragma unroll
    for (int i = 0; i < 4; i++) {
      const int r = sr + i * 32;
      GLD16(A + (size_t)(m0 + r) * K + kb + ssrc, &lA[r][sdst]);
      GLD16(Bw + (size_t)(n0 + r) * K + kb + ssrc, &lB[r][sdst]);
    }
    __syncthreads();
#pragma unroll
    for (int kk = 0; kk < 64; kk += 32) {
      short8 af[4], bf[4];
      const int cg = ((((kk >> 3) + (lane >> 4)) ^ (lane & 7)) << 3);
#pragma unroll
      for (int i = 0; i < 4; i++) {
        af[i] = *reinterpret_cast<const short8*>(&lA[wr + i * 16 + (lane & 15)][cg]);
        bf[i] = *reinterpret_cast<const short8*>(&lB[wc + i * 16 + (lane & 15)][cg]);
      }
#pragma unroll
      for (int mi = 0; mi < 4; mi++)
#pragma unroll
        for (int ni = 0; ni < 4; ni++)
          acc[mi][ni] = mfma16(af[mi], bf[ni], acc[mi][ni]);
    }
    __syncthreads();
  }
#pragma unroll
  for (int mi = 0; mi < 4; mi++) {
    const int row = m0 + wr + mi * 16 + ((lane >> 4) << 2);
#pragma unroll
    for (int ni = 0; ni < 4; ni++) {
      const int col = n0 + wc + ni * 16 + (lane & 15);
      if (col < Nreal) {
#pragma unroll
        for (int v = 0; v < 4; v++)
          C[(size_t)(row + v) * Nreal + col] = acc[mi][ni][v];
      }
    }
  }
}

// ------- causal depthwise conv (K=4) + SiLU -> bf16 xbc ---------------------
__global__ __launch_bounds__(256) void k_conv_silu(
    const float* __restrict__ projx, const float* __restrict__ cw,
    const float* __restrict__ cb, unsigned short* __restrict__ xbc) {
  const int ch = blockIdx.x * 256 + threadIdx.x;  // 17*256 = 4352 exact
  const int bt = blockIdx.y;
  const int b = bt >> 11, t = bt & 2047;
  float acc = cb[ch];
#pragma unroll
  for (int i = 0; i < 4; i++) {
    int tt = t - 3 + i;
    if (tt >= 0)
      acc += cw[ch * 4 + i] * projx[((size_t)b * LQ + tt) * PXW + ch];
  }
  float o = acc / (1.f + __expf(-acc));
  xbc[(size_t)bt * CONVD + ch] = f2bu(o);
}

// ------- dt softplus + per-chunk cumsum(dt*A): parallel 2-phase scan --------
__global__ __launch_bounds__(256) void k_dt(
    const float* __restrict__ projx, const float* __restrict__ dtb,
    const float* __restrict__ alog, float* __restrict__ dtv,
    float* __restrict__ dac) {
  const int bc = blockIdx.x;  // 16 = b*8+c
  const int b = bc >> 3, c = bc & 7;
  const int h = threadIdx.x & 63, q = threadIdx.x >> 6;
  const float bias = dtb[h];
  const float Ah = -__expf(alog[h]);
  const size_t base = (size_t)b * LQ + c * CHK + q * 64;
  float vals[64];
  float part = 0.f;
#pragma unroll
  for (int j = 0; j < 64; j++) {
    float raw = projx[(base + j) * PXW + CONVD + h] + bias;
    float dt = raw > 20.f ? raw : log1pf(__expf(raw));
    vals[j] = dt;
    dtv[(base + j) * NH + h] = dt;
    part += dt;
  }
  __shared__ float partials[4][64];
  partials[q][h] = part;
  __syncthreads();
  float cum = 0.f;
  for (int qq = 0; qq < q; qq++) cum += partials[qq][h];
  cum *= Ah;
#pragma unroll
  for (int j = 0; j < 64; j++) {
    cum += vals[j] * Ah;
    dac[(base + j) * NH + h] = cum;
  }
}

// ---------------- CB[t][s] = sum_n C[t][n]*B[s][n] per (b,c) ----------------
__global__ __launch_bounds__(256) void k_cb(const unsigned short* __restrict__ xbc,
                                            float* __restrict__ cbuf) {
  const int q = blockIdx.x;   // 4 quadrants
  const int bc = blockIdx.y;  // 16
  const int b = bc >> 3, c = bc & 7;
  const int qt = q >> 1, qs = q & 1;
  __shared__ unsigned short lC[128][136];
  __shared__ unsigned short lB[128][136];
  const int tid = threadIdx.x, lane = tid & 63, w = tid >> 6;
  {
    int r = tid >> 1, hf = tid & 1;
    size_t rowc = (size_t)b * LQ + c * CHK + qt * 128 + r;
    size_t rowb = (size_t)b * LQ + c * CHK + qs * 128 + r;
    const unsigned short* crp = xbc + rowc * CONVD + DIN + NST + hf * 64;
    const unsigned short* brp = xbc + rowb * CONVD + DIN + hf * 64;
#pragma unroll
    for (int n8 = 0; n8 < 8; n8++) {
      *reinterpret_cast<short8*>(&lC[r][hf * 64 + n8 * 8]) =
          *reinterpret_cast<const short8*>(crp + n8 * 8);
      *reinterpret_cast<short8*>(&lB[r][hf * 64 + n8 * 8]) =
          *reinterpret_cast<const short8*>(brp + n8 * 8);
    }
  }
  __syncthreads();
  const int wr = (w >> 1) * 64, wc = (w & 1) * 64;
  f32x4 acc[4][4] = {};
#pragma unroll
  for (int kk = 0; kk < 128; kk += 32) {
    short8 a[4], bb[4];
    const int ko = kk + ((lane >> 4) << 3);
#pragma unroll
    for (int i = 0; i < 4; i++) {
      a[i] = *reinterpret_cast<const short8*>(&lC[wr + i * 16 + (lane & 15)][ko]);
      bb[i] = *reinterpret_cast<const short8*>(&lB[wc + i * 16 + (lane & 15)][ko]);
    }
#pragma unroll
    for (int mi = 0; mi < 4; mi++)
#pragma unroll
      for (int ni = 0; ni < 4; ni++)
        acc[mi][ni] = mfma16(a[mi], bb[ni], acc[mi][ni]);
  }
  float* outp = cbuf + (size_t)bc * (CHK * CHK);
#pragma unroll
  for (int mi = 0; mi < 4; mi++) {
    const int t = qt * 128 + wr + mi * 16 + ((lane >> 4) << 2);
#pragma unroll
    for (int ni = 0; ni < 4; ni++) {
      const int s = qs * 128 + wc + ni * 16 + (lane & 15);
#pragma unroll
      for (int v = 0; v < 4; v++)
        outp[(size_t)(t + v) * CHK + s] = acc[mi][ni][v];
    }
  }
}

// ---------------- chunk states per (b,c,h): st = X^T (B*decay) -------------
// LDS 52KB -> 3 blocks/CU. st written bf16.
__global__ __launch_bounds__(256) void k_states(
    const unsigned short* __restrict__ xbc, const float* __restrict__ dtv,
    const float* __restrict__ dac, unsigned short* __restrict__ st) {
  const int h = blockIdx.x, c = blockIdx.y, b = blockIdx.z;
  const int cs = c * CHK;
  __shared__ unsigned short lXt[64][136];   // (p, s_loc)
  __shared__ unsigned short lBt[128][136];  // (n, s_loc)
  __shared__ float lda[256];
  const int tid = threadIdx.x, lane = tid & 63, w = tid >> 6;
  lda[tid] = dac[((size_t)b * LQ + cs + tid) * NH + h];
  __syncthreads();
  const float dalast = lda[255];
  f32x4 accS[4][2] = {};
  const int wn = w * 32;
  const int sl = tid & 127, sub = tid >> 7;
  for (int half = 0; half < 2; half++) {
    if (half) __syncthreads();
    {
      const int s = half * 128 + sl;
      const size_t row = (size_t)b * LQ + cs + s;
      const unsigned short* xrow = xbc + row * CONVD;
      const float dts = dtv[row * NH + h];
      const float dec = __expf(dalast - lda[s]);
#pragma unroll
      for (int g = 0; g < 4; g++) {
        short8 xv = *reinterpret_cast<const short8*>(xrow + h * HD + sub * 32 + g * 8);
#pragma unroll
        for (int u = 0; u < 8; u++)
          lXt[sub * 32 + g * 8 + u][sl] = f2bu(b2f((unsigned short)xv[u]) * dts);
      }
#pragma unroll
      for (int g = 0; g < 8; g++) {
        short8 bv = *reinterpret_cast<const short8*>(xrow + DIN + sub * 64 + g * 8);
#pragma unroll
        for (int u = 0; u < 8; u++)
          lBt[sub * 64 + g * 8 + u][sl] = f2bu(b2f((unsigned short)bv[u]) * dec);
      }
    }
    __syncthreads();
    for (int sb4 = 0; sb4 < 4; sb4++) {
      short8 xf[4], btf[2];
      const int so = sb4 * 32 + ((lane >> 4) << 3);
#pragma unroll
      for (int i = 0; i < 4; i++)
        xf[i] = *reinterpret_cast<const short8*>(&lXt[i * 16 + (lane & 15)][so]);
#pragma unroll
      for (int i = 0; i < 2; i++)
        btf[i] = *reinterpret_cast<const short8*>(&lBt[wn + i * 16 + (lane & 15)][so]);
#pragma unroll
      for (int mi = 0; mi < 4; mi++)
#pragma unroll
        for (int nj = 0; nj < 2; nj++)
          accS[mi][nj] = mfma16(xf[mi], btf[nj], accS[mi][nj]);
    }
  }
  unsigned short* stp = st + ((size_t)((b * NCH + c) * NH + h)) * (HD * NST);
#pragma unroll
  for (int mi = 0; mi < 4; mi++) {
    const int p = mi * 16 + ((lane >> 4) << 2);
#pragma unroll
    for (int nj = 0; nj < 2; nj++) {
      const int n = wn + nj * 16 + (lane & 15);
#pragma unroll
      for (int v = 0; v < 4; v++)
        stp[(size_t)(p + v) * NST + n] = f2bu(accS[mi][nj][v]);
    }
  }
}

// ---------------- inter-chunk state scan (st bf16 -> pv bf16) ---------------
__global__ void k_scan(const unsigned short* __restrict__ st,
                       const float* __restrict__ dac,
                       unsigned short* __restrict__ pv) {
  const int h = blockIdx.x, b = blockIdx.y;
  const int tid = threadIdx.x;
  float P[32];
#pragma unroll
  for (int j = 0; j < 32; j++) P[j] = 0.f;
  for (int c = 0; c < NCH; c++) {
    const size_t base = ((size_t)((b * NCH + c) * NH + h)) * (HD * NST);
#pragma unroll
    for (int j = 0; j < 32; j++) pv[base + tid + 256 * j] = f2bu(P[j]);
    const float d = __expf(dac[((size_t)b * LQ + c * CHK + 255) * NH + h]);
#pragma unroll
    for (int j = 0; j < 32; j++) P[j] = P[j] * d + b2f(st[base + tid + 256 * j]);
  }
}

// -------- fused Y = Y_diag + Y_off + D*x per (b,c,h), single y write --------
// Y_off folded in as 4 "virtual s-blocks": lS <- C[t][n]*e^{da_t} (<=1, safe),
// lXt <- prev[p][n] from pv. LDS ~40KB -> 4 blocks/CU.
__global__ __launch_bounds__(256) void k_y(
    const unsigned short* __restrict__ xbc, const float* __restrict__ dtv,
    const float* __restrict__ dac, const float* __restrict__ cbuf,
    const unsigned short* __restrict__ pv, const float* __restrict__ Dp,
    float* __restrict__ y) {
  const int h = blockIdx.x, c = blockIdx.y, b = blockIdx.z;
  const int cs = c * CHK;
  __shared__ unsigned short lXt[64][136];
  __shared__ unsigned short lS[256][40];
  __shared__ float lda[256];
  __shared__ float lesE[256];
  const int tid = threadIdx.x, lane = tid & 63, w = tid >> 6;
  lda[tid] = dac[((size_t)b * LQ + cs + tid) * NH + h];
  __syncthreads();
  lesE[tid] = __expf(lda[tid | 31] - lda[tid]);
  const float da_t = lda[tid];
  const float* cbp = cbuf + ((size_t)(b * NCH + c)) * (CHK * CHK);
  f32x4 accY[4][4] = {};
  const int sl = tid & 127, sub = tid >> 7;
  // ---- diagonal part: s in [0,256)
  for (int half = 0; half < 2; half++) {
    {
      const int s = half * 128 + sl;
      const size_t row = (size_t)b * LQ + cs + s;
      const unsigned short* xrow = xbc + row * CONVD;
      const float dts = dtv[row * NH + h];
#pragma unroll
      for (int g = 0; g < 4; g++) {
        short8 xv = *reinterpret_cast<const short8*>(xrow + h * HD + sub * 32 + g * 8);
#pragma unroll
        for (int u = 0; u < 8; u++)
          lXt[sub * 32 + g * 8 + u][sl] = f2bu(b2f((unsigned short)xv[u]) * dts);
      }
    }
    __syncthreads();
    for (int sb4 = 0; sb4 < 4; sb4++) {
      const int sb = half * 4 + sb4;
      {
        const int t = tid;
        const int tb = t >> 5;
        if (tb > sb) {
          const float et = __expf(da_t - lda[sb * 32 + 31]);
          const f32x4* cr = reinterpret_cast<const f32x4*>(cbp + (size_t)t * CHK + sb * 32);
          f32x4 vv[8];
#pragma unroll
          for (int j4 = 0; j4 < 8; j4++) vv[j4] = cr[j4];
#pragma unroll
          for (int g = 0; g < 4; g++) {
            short8 pk;
#pragma unroll
            for (int e = 0; e < 8; e++) {
              const int j = g * 8 + e;
              pk[e] = (short)f2bu(vv[j >> 2][j & 3] * et * lesE[sb * 32 + j]);
            }
            *reinterpret_cast<short8*>(&lS[t][g * 8]) = pk;
          }
        } else if (tb == sb) {
          const f32x4* cr = reinterpret_cast<const f32x4*>(cbp + (size_t)t * CHK + sb * 32);
          f32x4 vv[8];
#pragma unroll
          for (int j4 = 0; j4 < 8; j4++) vv[j4] = cr[j4];
          const int tl = t & 31;
#pragma unroll
          for (int g = 0; g < 4; g++) {
            short8 pk;
#pragma unroll
            for (int e = 0; e < 8; e++) {
              const int j = g * 8 + e;
              float val = (j <= tl)
                  ? vv[j >> 2][j & 3] * __expf(da_t - lda[sb * 32 + j]) : 0.f;
              pk[e] = (short)f2bu(val);
            }
            *reinterpret_cast<short8*>(&lS[t][g * 8]) = pk;
          }
        } else {
          short8 z = {};
#pragma unroll
          for (int g = 0; g < 4; g++)
            *reinterpret_cast<short8*>(&lS[tid][g * 8]) = z;
        }
      }
      __syncthreads();
      short8 sf[4], xf[4];
      const int ko = ((lane >> 4) << 3);
      const int so = sb4 * 32 + ko;
#pragma unroll
      for (int i = 0; i < 4; i++) {
        sf[i] = *reinterpret_cast<const short8*>(&lS[w * 64 + i * 16 + (lane & 15)][ko]);
        xf[i] = *reinterpret_cast<const short8*>(&lXt[i * 16 + (lane & 15)][so]);
      }
#pragma unroll
      for (int mi = 0; mi < 4; mi++)
#pragma unroll
        for (int ni = 0; ni < 4; ni++)
          accY[mi][ni] = mfma16(sf[mi], xf[ni], accY[mi][ni]);
      __syncthreads();
    }
  }
  // ---- off part: 4 virtual s-blocks over n in [0,128)
  {
    // stage lXt <- prev[p][n] (bf16 copy from pv)
    const unsigned short* pr =
        pv + ((size_t)((b * NCH + c) * NH + h)) * (HD * NST);
    const int p = tid >> 2, qtr = tid & 3;
#pragma unroll
    for (int g = 0; g < 4; g++)
      *reinterpret_cast<short8*>(&lXt[p][qtr * 32 + g * 8]) =
          *reinterpret_cast<const short8*>(pr + (size_t)p * NST + qtr * 32 + g * 8);
  }
  __syncthreads();
  const float et_self = __expf(da_t);  // da_t <= 0, safe
  const unsigned short* crow =
      xbc + ((size_t)b * LQ + cs + tid) * CONVD + DIN + NST;
  for (int sb4 = 0; sb4 < 4; sb4++) {
    {
#pragma unroll
      for (int g = 0; g < 4; g++) {
        short8 cv = *reinterpret_cast<const short8*>(crow + sb4 * 32 + g * 8);
        short8 pk;
#pragma unroll
        for (int e = 0; e < 8; e++)
          pk[e] = (short)f2bu(b2f((unsigned short)cv[e]) * et_self);
        *reinterpret_cast<short8*>(&lS[tid][g * 8]) = pk;
      }
    }
    __syncthreads();
    short8 sf[4], xf[4];
    const int ko = ((lane >> 4) << 3);
    const int so = sb4 * 32 + ko;
#pragma unroll
    for (int i = 0; i < 4; i++) {
      sf[i] = *reinterpret_cast<const short8*>(&lS[w * 64 + i * 16 + (lane & 15)][ko]);
      xf[i] = *reinterpret_cast<const short8*>(&lXt[i * 16 + (lane & 15)][so]);
    }
#pragma unroll
    for (int mi = 0; mi < 4; mi++)
#pragma unroll
      for (int ni = 0; ni < 4; ni++)
        accY[mi][ni] = mfma16(sf[mi], xf[ni], accY[mi][ni]);
    __syncthreads();
  }
  // ---- epilogue: y = accY + D*x (single write)
  const float Dh = Dp[h];
#pragma unroll
  for (int mi = 0; mi < 4; mi++) {
    const int t = w * 64 + mi * 16 + ((lane >> 4) << 2);
#pragma unroll
    for (int ni = 0; ni < 4; ni++) {
      const int p = ni * 16 + (lane & 15);
#pragma unroll
      for (int v = 0; v < 4; v++) {
        const size_t row = (size_t)b * LQ + cs + t + v;
        const float xval = b2f(xbc[row * CONVD + h * HD + p]);
        y[row * DIN + h * HD + p] = accY[mi][ni][v] + Dh * xval;
      }
    }
  }
}

// ---------------- gate*silu + RMSNorm -> bf16 (vectorized) ------------------
__global__ __launch_bounds__(256) void k_gatenorm(
    const float* __restrict__ y, const unsigned short* __restrict__ gateb,
    const float* __restrict__ nw, unsigned short* __restrict__ hgb) {
  const int r = blockIdx.x;
  const int tid = threadIdx.x;
  const int d0 = tid * 16;
  const float* yr = y + (size_t)r * DIN + d0;
  const unsigned short* gr = gateb + (size_t)r * DIN + d0;
  f32x4 yv[4];
  short8 gv[2];
#pragma unroll
  for (int q = 0; q < 4; q++) yv[q] = reinterpret_cast<const f32x4*>(yr)[q];
#pragma unroll
  for (int q = 0; q < 2; q++) gv[q] = reinterpret_cast<const short8*>(gr)[q];
  float hg[16];
  float ss = 0.f;
#pragma unroll
  for (int j = 0; j < 16; j++) {
    const float g = b2f((unsigned short)gv[j >> 3][j & 7]);
    const float v = yv[j >> 2][j & 3] * (g / (1.f + __expf(-g)));
    hg[j] = v;
    ss += v * v;
  }
#pragma unroll
  for (int o = 32; o > 0; o >>= 1) ss += __shfl_down(ss, o);
  __shared__ float red[4];
  if ((tid & 63) == 0) red[tid >> 6] = ss;
  __syncthreads();
  const float tot = red[0] + red[1] + red[2] + red[3];
  const float scale = rsqrtf(tot / (float)DIN + 1e-5f);
  const float* nr = nw + d0;
  short8 o0, o1;
#pragma unroll
  for (int j = 0; j < 16; j++) {
    const unsigned short ov = f2bu(hg[j] * scale * nr[j]);
    if (j < 8) o0[j] = (short)ov;
    else o1[j - 8] = (short)ov;
  }
  unsigned short* hp = hgb + (size_t)r * DIN + d0;
  *reinterpret_cast<short8*>(hp) = o0;
  *reinterpret_cast<short8*>(hp + 8) = o1;
}

extern "C" void kernel_launch(void* const* d_in, const int* in_sizes, int n_in,
                              void* d_out, int out_size, void* d_ws, size_t ws_size,
                              hipStream_t stream) {
  const float* hidden = (const float*)d_in[0];
  const float* w1 = (const float*)d_in[1];
  const float* cw = (const float*)d_in[2];
  const float* cb = (const float*)d_in[3];
  const float* dtb = (const float*)d_in[4];
  const float* alog = (const float*)d_in[5];
  const float* Dp = (const float*)d_in[6];
  const float* nw = (const float*)d_in[7];
  const float* w2 = (const float*)d_in[8];
  float* out = (float*)d_out;
  char* ws = (char*)d_ws;

  // Lifetime-aliased layout. W2B has a DEDICATED region (written S1, read S5).
  const size_t OFF_GATEB = 0;            // bf16 4096x4096   S1-S4
  const size_t OFF_XBC = 33554432;       // bf16 4096x4352   S2-S3
  const size_t OFF_DTV = 104857600;      // f32 4096x64      S2-S3
  const size_t OFF_DAC = 105906176;      // f32 4096x64      S2-S3
  const size_t OFF_CB = 106954752;       // f32 16x256x256   S3
  const size_t OFF_Y = 111149056;        // f32 4096x4096    S3-S4
  const size_t OFF_ST = 178257920;       // bf16 1024x64x128 S3
  const size_t OFF_PV = 211812352;       // bf16 1024x64x128 S3
  const size_t OFF_PROJX = 111149056;    // f32 4096x4416    S1-S2 (aliases Y head)
  const size_t OFF_HB = 183500800;       // bf16 4096x2048   S1 (aliases ST tail)
  const size_t OFF_W1B = 200278016;      // bf16 8704x2048   S1 (aliases PV)
  const size_t OFF_W2B = 245366784;      // bf16 2048x4096   S1-S5 DEDICATED
  const size_t OFF_HGB = 33554432;       // bf16 4096x4096   S4-S5 (aliases XBC)
  const size_t NEED = 262144000;
  if (ws_size < NEED) {
    fprintf(stderr, "WS TOO SMALL: %zu < %zu\n", ws_size, NEED);
    return;
  }
  unsigned short* gateb = (unsigned short*)(ws + OFF_GATEB);
  unsigned short* xbc = (unsigned short*)(ws + OFF_XBC);
  float* dtv = (float*)(ws + OFF_DTV);
  float* dac = (float*)(ws + OFF_DAC);
  float* cbuf = (float*)(ws + OFF_CB);
  float* y = (float*)(ws + OFF_Y);
  unsigned short* st = (unsigned short*)(ws + OFF_ST);
  unsigned short* pv = (unsigned short*)(ws + OFF_PV);
  float* projx = (float*)(ws + OFF_PROJX);
  unsigned short* hb = (unsigned short*)(ws + OFF_HB);
  unsigned short* w1b = (unsigned short*)(ws + OFF_W1B);
  unsigned short* w2b = (unsigned short*)(ws + OFF_W2B);
  unsigned short* hgb = (unsigned short*)(ws + OFF_HGB);

  // S1: fused vectorized casts, then GEMM1
  k_cast3<<<4096, 256, 0, stream>>>(hidden, hb, (long)BL * DMODEL,
                                    w1, w1b, (long)PROJD * DMODEL,
                                    (long)PROJ_PAD2 * DMODEL,
                                    w2, w2b, (long)DMODEL * DIN);
  k_gemm256<true><<<dim3(PROJ_PAD2 / 256, BL / 256), 512, 0, stream>>>(
      hb, w1b, nullptr, gateb, projx, PROJD, DMODEL);
  // S2
  k_conv_silu<<<dim3(17, BL), 256, 0, stream>>>(projx, cw, cb, xbc);
  k_dt<<<16, 256, 0, stream>>>(projx, dtb, alog, dtv, dac);
  // S3
  k_cb<<<dim3(4, 16), 256, 0, stream>>>(xbc, cbuf);
  k_states<<<dim3(NH, NCH, BB), 256, 0, stream>>>(xbc, dtv, dac, st);
  k_scan<<<dim3(NH, BB), 256, 0, stream>>>(st, dac, pv);
  k_y<<<dim3(NH, NCH, BB), 256, 0, stream>>>(xbc, dtv, dac, cbuf, pv, Dp, y);
  // S4
  k_gatenorm<<<BL, 256, 0, stream>>>(y, gateb, nw, hgb);
  // S5
  k_gemm_bt<<<dim3(DMODEL / 128, BL / 128), 256, 0, stream>>>(
      hgb, w2b, out, DMODEL, DIN);
}

// Round 13
// 531.583 us; speedup vs baseline: 1.5302x; 1.0349x over previous
//
#include <hip/hip_runtime.h>
#include <hip/hip_bf16.h>
#include <cstdio>

#define LQ 2048      // L
#define BB 2         // batch
#define BL 4096      // B*L rows
#define DMODEL 2048
#define DIN 4096
#define NH 64
#define HD 64
#define NST 128
#define CONVD 4352
#define PROJD 8512
#define PROJ_PAD2 8704   // pad to 256 multiple for 256-tile GEMM1
#define PXW 4416     // projx width: CONVD + NH
#define CHK 256
#define NCH 8        // chunks per batch

typedef __attribute__((ext_vector_type(8))) short short8;
typedef __attribute__((ext_vector_type(4))) float f32x4;

__device__ __forceinline__ unsigned short f2bu(float x) {
  __hip_bfloat16 h = __float2bfloat16(x);
  return __builtin_bit_cast(unsigned short, h);
}

__device__ __forceinline__ float b2f(unsigned short u) {
  return __bfloat162float(__builtin_bit_cast(__hip_bfloat16, u));
}

__device__ __forceinline__ f32x4 mfma16(short8 a, short8 b, f32x4 c) {
  return __builtin_amdgcn_mfma_f32_16x16x32_bf16(a, b, c, 0, 0, 0);
}

#define GLD16(gptr, lptr)                                                  \
  __builtin_amdgcn_global_load_lds(                                        \
      (const __attribute__((address_space(1))) void*)(gptr),               \
      (__attribute__((address_space(3))) void*)(lptr), 16, 0, 0)

// ------- fused vectorized cast fp32 -> bf16 for hb / w1b(+pad) / w2b --------
__global__ void k_cast3(const float* __restrict__ s0, unsigned short* __restrict__ d0,
                        long n0,
                        const float* __restrict__ s1, unsigned short* __restrict__ d1,
                        long n1r, long n1t,
                        const float* __restrict__ s2, unsigned short* __restrict__ d2,
                        long n2) {
  const long ntot8 = (n0 + n1t + n2) >> 3;
  long i = (long)blockIdx.x * blockDim.x + threadIdx.x;
  const long stride = (long)gridDim.x * blockDim.x;
  for (; i < ntot8; i += stride) {
    const long e = i << 3;
    const float* src;
    unsigned short* dst;
    long rel, nreal;
    if (e < n0) { src = s0; dst = d0; rel = e; nreal = n0; }
    else if (e < n0 + n1t) { src = s1; dst = d1; rel = e - n0; nreal = n1r; }
    else { src = s2; dst = d2; rel = e - n0 - n1t; nreal = n2; }
    short8 pk;
    if (rel + 8 <= nreal) {
      const f32x4* sp = reinterpret_cast<const f32x4*>(src + rel);
      f32x4 v0 = sp[0], v1 = sp[1];
#pragma unroll
      for (int u = 0; u < 4; u++) {
        pk[u] = (short)f2bu(v0[u]);
        pk[4 + u] = (short)f2bu(v1[u]);
      }
    } else {
#pragma unroll
      for (int u = 0; u < 8; u++)
        pk[u] = (rel + u < nreal) ? (short)f2bu(src[rel + u]) : (short)0;
    }
    *reinterpret_cast<short8*>(dst + rel) = pk;
  }
}

// swizzled fragment read from a [256][64] bf16 LDS tile (involution: cg ^= row&7)
__device__ __forceinline__ short8 rdfrag(const unsigned short (*mp)[64], int rowbase,
                                         int lane, int kh) {
  const int row = rowbase + (lane & 15);
  const int cg = (((kh << 2) + (lane >> 4)) ^ (lane & 7)) << 3;
  return *reinterpret_cast<const short8*>(&mp[row][cg]);
}

// ==== 256x256 GEMM, counted-vmcnt pipeline =================================
// R12 post-mortem: barriers after phase0/phase2 protect nothing (all phases
// read buf[cur], stage buf[nxt]) — removed. Only the two vmcnt+barrier pairs
// that make the counted-wait invariants global remain.
template <bool SPLIT>
__global__ __launch_bounds__(512) void k_gemm256(
    const unsigned short* __restrict__ A, const unsigned short* __restrict__ Bw,
    float* __restrict__ C, unsigned short* __restrict__ gateb,
    float* __restrict__ projx, int Nreal, int K) {
  __shared__ unsigned short sh[2][2][256][64];  // [buf][A/B][row][col]
  const int tid = threadIdx.x;
  const int lane = tid & 63, w = tid >> 6;
  const int wm = w >> 2, wn2 = w & 3;
  const int gx = gridDim.x;
  const int nwg = gx * gridDim.y;
  const int bid = blockIdx.y * gx + blockIdx.x;
  const int qq = nwg >> 3;
  const int swz = (bid & 7) * qq + (bid >> 3);
  const int m0 = (swz / gx) * 256, n0 = (swz % gx) * 256;
  const int srow = tid >> 3;
  const int sdst = (tid & 7) * 8;                       // linear LDS col
  const int ssrc = ((tid & 7) ^ ((tid >> 3) & 7)) * 8;  // swizzled gmem col
  const unsigned short* Ab = A + (size_t)m0 * K;
  const unsigned short* Bb = Bw + (size_t)n0 * K;

#define ST(bf, mt, MP, r0, kk)                                             \
  GLD16(MP + (size_t)((r0) + srow) * K + (kk) + ssrc,                      \
        &sh[bf][mt][(r0) + srow][sdst])

  f32x4 acc[8][4] = {};
  const int nt = K >> 6;

  // prologue: stage tile 0 fully, in canonical round order
  ST(0, 0, Ab, 0, 0);   ST(0, 0, Ab, 128, 0);
  ST(0, 1, Bb, 0, 0);   ST(0, 1, Bb, 64, 0);
  ST(0, 1, Bb, 128, 0); ST(0, 1, Bb, 192, 0);
  ST(0, 0, Ab, 64, 0);  ST(0, 0, Ab, 192, 0);

#define DO_PHASE(P)                                                        \
  {                                                                        \
    const int rb = wm * 128 + (P) * 32;                                    \
    short8 a00 = rdfrag(sh[cur][0], rb, lane, 0);                          \
    short8 a01 = rdfrag(sh[cur][0], rb, lane, 1);                          \
    short8 a10 = rdfrag(sh[cur][0], rb + 16, lane, 0);                     \
    short8 a11 = rdfrag(sh[cur][0], rb + 16, lane, 1);                     \
    __builtin_amdgcn_s_setprio(1);                                         \
    _Pragma("unroll")                                                      \
    for (int nf = 0; nf < 4; nf++) {                                       \
      acc[2 * (P)][nf] = mfma16(a00, bfr[nf][0], acc[2 * (P)][nf]);        \
      acc[2 * (P)][nf] = mfma16(a01, bfr[nf][1], acc[2 * (P)][nf]);        \
      acc[2 * (P) + 1][nf] = mfma16(a10, bfr[nf][0], acc[2 * (P) + 1][nf]);\
      acc[2 * (P) + 1][nf] = mfma16(a11, bfr[nf][1], acc[2 * (P) + 1][nf]);\
    }                                                                      \
    __builtin_amdgcn_s_setprio(0);                                         \
  }

  for (int t = 0; t < nt; ++t) {
    const int cur = t & 1, nxt = cur ^ 1;
    const int kbn = (t + 1) << 6;
    const bool more = (t + 1 < nt);
    // entry: tile t rounds 0..5 (A0,A2,B0..B3) landed globally
    asm volatile("s_waitcnt vmcnt(2)" ::: "memory");
    __builtin_amdgcn_s_barrier();
    // ---- half 1: stage A0,A2 + B0,B1 of t+1; phases 0,1 (A rows 0-63/128-191)
    if (more) { ST(nxt, 0, Ab, 0, kbn); ST(nxt, 0, Ab, 128, kbn); }
    short8 bfr[4][2];
#pragma unroll
    for (int nf = 0; nf < 4; nf++) {
      bfr[nf][0] = rdfrag(sh[cur][1], wn2 * 64 + nf * 16, lane, 0);
      bfr[nf][1] = rdfrag(sh[cur][1], wn2 * 64 + nf * 16, lane, 1);
    }
    DO_PHASE(0)
    if (more) { ST(nxt, 1, Bb, 0, kbn); ST(nxt, 1, Bb, 64, kbn); }
    DO_PHASE(1)
    // mid wait: tile t rounds A1,A3 landed globally
    if (more) asm volatile("s_waitcnt vmcnt(4)" ::: "memory");
    else      asm volatile("s_waitcnt vmcnt(0)" ::: "memory");
    __builtin_amdgcn_s_barrier();
    // ---- half 2: stage B2,B3 + A1,A3 of t+1; phases 2,3 (A rows 64-127/192-255)
    if (more) { ST(nxt, 1, Bb, 128, kbn); ST(nxt, 1, Bb, 192, kbn); }
    DO_PHASE(2)
    if (more) { ST(nxt, 0, Ab, 64, kbn); ST(nxt, 0, Ab, 192, kbn); }
    DO_PHASE(3)
    // no trailing barrier: next tile's entry vmcnt+barrier covers it
  }
#undef DO_PHASE
#undef ST

  // epilogue
#pragma unroll
  for (int mf = 0; mf < 8; mf++) {
    const int row = m0 + wm * 128 + mf * 16 + ((lane >> 4) << 2);
#pragma unroll
    for (int nf = 0; nf < 4; nf++) {
      const int col = n0 + wn2 * 64 + nf * 16 + (lane & 15);
      if (SPLIT) {
        if (col < DIN) {
#pragma unroll
          for (int v = 0; v < 4; v++)
            gateb[(size_t)(row + v) * DIN + col] = f2bu(acc[mf][nf][v]);
        } else if (col < PROJD) {
#pragma unroll
          for (int v = 0; v < 4; v++)
            projx[(size_t)(row + v) * PXW + (col - DIN)] = acc[mf][nf][v];
        }
      } else {
        if (col < Nreal) {
#pragma unroll
          for (int v = 0; v < 4; v++)
            C[(size_t)(row + v) * Nreal + col] = acc[mf][nf][v];
        }
      }
    }
  }
}

// ---- 128x128 bf16 GEMM (R4 proven) — used for GEMM2 (512 blocks, 2 rounds) -
__global__ __launch_bounds__(256) void k_gemm_bt(
    const unsigned short* __restrict__ A, const unsigned short* __restrict__ Bw,
    float* __restrict__ C, int Nreal, int K) {
  __shared__ unsigned short lA[128][64];
  __shared__ unsigned short lB[128][64];
  const int tid = threadIdx.x;
  const int lane = tid & 63, w = tid >> 6;
  const int gx = gridDim.x;
  const int nwg = gx * gridDim.y;
  const int bid = blockIdx.y * gx + blockIdx.x;
  const int qq = nwg >> 3;
  const int swz = (bid & 7) * qq + (bid >> 3);
  const int m0 = (swz / gx) * 128, n0 = (swz % gx) * 128;
  const int wr = (w >> 1) * 64, wc = (w & 1) * 64;
  const int sr = tid >> 3;
  const int sdst = (tid & 7) * 8;
  const int ssrc = ((tid & 7) ^ ((tid >> 3) & 7)) * 8;
  f32x4 acc[4][4] = {};
  for (int kb = 0; kb < K; kb += 64) {
#pragma unroll
    for (int i = 0; i < 4; i++) {
      const int r = sr + i * 32;
      GLD16(A + (size_t)(m0 + r) * K + kb + ssrc, &lA[r][sdst]);
      GLD16(Bw + (size_t)(n0 + r) * K + kb + ssrc, &lB[r][sdst]);
    }
    __syncthreads();
#pragma unroll
    for (int kk = 0; kk < 64; kk += 32) {
      short8 af[4], bf[4];
      const int cg = ((((kk >> 3) + (lane >> 4)) ^ (lane & 7)) << 3);
#pragma unroll
      for (int i = 0; i < 4; i++) {
        af[i] = *reinterpret_cast<const short8*>(&lA[wr + i * 16 + (lane & 15)][cg]);
        bf[i] = *reinterpret_cast<const short8*>(&lB[wc + i * 16 + (lane & 15)][cg]);
      }
#pragma unroll
      for (int mi = 0; mi < 4; mi++)
#pragma unroll
        for (int ni = 0; ni < 4; ni++)
          acc[mi][ni] = mfma16(af[mi], bf[ni], acc[mi][ni]);
    }
    __syncthreads();
  }
#pragma unroll
  for (int mi = 0; mi < 4; mi++) {
    const int row = m0 + wr + mi * 16 + ((lane >> 4) << 2);
#pragma unroll
    for (int ni = 0; ni < 4; ni++) {
      const int col = n0 + wc + ni * 16 + (lane & 15);
      if (col < Nreal) {
#pragma unroll
        for (int v = 0; v < 4; v++)
          C[(size_t)(row + v) * Nreal + col] = acc[mi][ni][v];
      }
    }
  }
}

// ------- causal depthwise conv (K=4) + SiLU -> bf16 xbc ---------------------
__global__ __launch_bounds__(256) void k_conv_silu(
    const float* __restrict__ projx, const float* __restrict__ cw,
    const float* __restrict__ cb, unsigned short* __restrict__ xbc) {
  const int ch = blockIdx.x * 256 + threadIdx.x;  // 17*256 = 4352 exact
  const int bt = blockIdx.y;
  const int b = bt >> 11, t = bt & 2047;
  float acc = cb[ch];
#pragma unroll
  for (int i = 0; i < 4; i++) {
    int tt = t - 3 + i;
    if (tt >= 0)
      acc += cw[ch * 4 + i] * projx[((size_t)b * LQ + tt) * PXW + ch];
  }
  float o = acc / (1.f + __expf(-acc));
  xbc[(size_t)bt * CONVD + ch] = f2bu(o);
}

// ------- dt softplus + per-chunk cumsum(dt*A): 512-thread 2-phase scan ------
__global__ __launch_bounds__(512) void k_dt(
    const float* __restrict__ projx, const float* __restrict__ dtb,
    const float* __restrict__ alog, float* __restrict__ dtv,
    float* __restrict__ dac) {
  const int bc = blockIdx.x;  // 16 = b*8+c
  const int b = bc >> 3, c = bc & 7;
  const int h = threadIdx.x & 63, q = threadIdx.x >> 6;  // q in [0,8)
  const float bias = dtb[h];
  const float Ah = -__expf(alog[h]);
  const size_t base = (size_t)b * LQ + c * CHK + q * 32;
  float vals[32];
  float part = 0.f;
#pragma unroll
  for (int j = 0; j < 32; j++) {
    float raw = projx[(base + j) * PXW + CONVD + h] + bias;
    float dt = raw > 20.f ? raw : log1pf(__expf(raw));
    vals[j] = dt;
    dtv[(base + j) * NH + h] = dt;
    part += dt;
  }
  __shared__ float partials[8][64];
  partials[q][h] = part;
  __syncthreads();
  float cum = 0.f;
  for (int qq = 0; qq < q; qq++) cum += partials[qq][h];
  cum *= Ah;
#pragma unroll
  for (int j = 0; j < 32; j++) {
    cum += vals[j] * Ah;
    dac[(base + j) * NH + h] = cum;
  }
}

// ---------------- CB[t][s] = sum_n C[t][n]*B[s][n] per (b,c) ----------------
__global__ __launch_bounds__(256) void k_cb(const unsigned short* __restrict__ xbc,
                                            float* __restrict__ cbuf) {
  const int q = blockIdx.x;   // 4 quadrants
  const int bc = blockIdx.y;  // 16
  const int b = bc >> 3, c = bc & 7;
  const int qt = q >> 1, qs = q & 1;
  __shared__ unsigned short lC[128][136];
  __shared__ unsigned short lB[128][136];
  const int tid = threadIdx.x, lane = tid & 63, w = tid >> 6;
  {
    int r = tid >> 1, hf = tid & 1;
    size_t rowc = (size_t)b * LQ + c * CHK + qt * 128 + r;
    size_t rowb = (size_t)b * LQ + c * CHK + qs * 128 + r;
    const unsigned short* crp = xbc + rowc * CONVD + DIN + NST + hf * 64;
    const unsigned short* brp = xbc + rowb * CONVD + DIN + hf * 64;
#pragma unroll
    for (int n8 = 0; n8 < 8; n8++) {
      *reinterpret_cast<short8*>(&lC[r][hf * 64 + n8 * 8]) =
          *reinterpret_cast<const short8*>(crp + n8 * 8);
      *reinterpret_cast<short8*>(&lB[r][hf * 64 + n8 * 8]) =
          *reinterpret_cast<const short8*>(brp + n8 * 8);
    }
  }
  __syncthreads();
  const int wr = (w >> 1) * 64, wc = (w & 1) * 64;
  f32x4 acc[4][4] = {};
#pragma unroll
  for (int kk = 0; kk < 128; kk += 32) {
    short8 a[4], bb[4];
    const int ko = kk + ((lane >> 4) << 3);
#pragma unroll
    for (int i = 0; i < 4; i++) {
      a[i] = *reinterpret_cast<const short8*>(&lC[wr + i * 16 + (lane & 15)][ko]);
      bb[i] = *reinterpret_cast<const short8*>(&lB[wc + i * 16 + (lane & 15)][ko]);
    }
#pragma unroll
    for (int mi = 0; mi < 4; mi++)
#pragma unroll
      for (int ni = 0; ni < 4; ni++)
        acc[mi][ni] = mfma16(a[mi], bb[ni], acc[mi][ni]);
  }
  float* outp = cbuf + (size_t)bc * (CHK * CHK);
#pragma unroll
  for (int mi = 0; mi < 4; mi++) {
    const int t = qt * 128 + wr + mi * 16 + ((lane >> 4) << 2);
#pragma unroll
    for (int ni = 0; ni < 4; ni++) {
      const int s = qs * 128 + wc + ni * 16 + (lane & 15);
#pragma unroll
      for (int v = 0; v < 4; v++)
        outp[(size_t)(t + v) * CHK + s] = acc[mi][ni][v];
    }
  }
}

// ---------------- chunk states per (b,c,h): st = X^T (B*decay) -------------
__global__ __launch_bounds__(256) void k_states(
    const unsigned short* __restrict__ xbc, const float* __restrict__ dtv,
    const float* __restrict__ dac, unsigned short* __restrict__ st) {
  const int h = blockIdx.x, c = blockIdx.y, b = blockIdx.z;
  const int cs = c * CHK;
  __shared__ unsigned short lXt[64][136];   // (p, s_loc)
  __shared__ unsigned short lBt[128][136];  // (n, s_loc)
  __shared__ float lda[256];
  const int tid = threadIdx.x, lane = tid & 63, w = tid >> 6;
  lda[tid] = dac[((size_t)b * LQ + cs + tid) * NH + h];
  __syncthreads();
  const float dalast = lda[255];
  f32x4 accS[4][2] = {};
  const int wn = w * 32;
  const int sl = tid & 127, sub = tid >> 7;
  for (int half = 0; half < 2; half++) {
    if (half) __syncthreads();
    {
      const int s = half * 128 + sl;
      const size_t row = (size_t)b * LQ + cs + s;
      const unsigned short* xrow = xbc + row * CONVD;
      const float dts = dtv[row * NH + h];
      const float dec = __expf(dalast - lda[s]);
#pragma unroll
      for (int g = 0; g < 4; g++) {
        short8 xv = *reinterpret_cast<const short8*>(xrow + h * HD + sub * 32 + g * 8);
#pragma unroll
        for (int u = 0; u < 8; u++)
          lXt[sub * 32 + g * 8 + u][sl] = f2bu(b2f((unsigned short)xv[u]) * dts);
      }
#pragma unroll
      for (int g = 0; g < 8; g++) {
        short8 bv = *reinterpret_cast<const short8*>(xrow + DIN + sub * 64 + g * 8);
#pragma unroll
        for (int u = 0; u < 8; u++)
          lBt[sub * 64 + g * 8 + u][sl] = f2bu(b2f((unsigned short)bv[u]) * dec);
      }
    }
    __syncthreads();
    for (int sb4 = 0; sb4 < 4; sb4++) {
      short8 xf[4], btf[2];
      const int so = sb4 * 32 + ((lane >> 4) << 3);
#pragma unroll
      for (int i = 0; i < 4; i++)
        xf[i] = *reinterpret_cast<const short8*>(&lXt[i * 16 + (lane & 15)][so]);
#pragma unroll
      for (int i = 0; i < 2; i++)
        btf[i] = *reinterpret_cast<const short8*>(&lBt[wn + i * 16 + (lane & 15)][so]);
#pragma unroll
      for (int mi = 0; mi < 4; mi++)
#pragma unroll
        for (int nj = 0; nj < 2; nj++)
          accS[mi][nj] = mfma16(xf[mi], btf[nj], accS[mi][nj]);
    }
  }
  unsigned short* stp = st + ((size_t)((b * NCH + c) * NH + h)) * (HD * NST);
#pragma unroll
  for (int mi = 0; mi < 4; mi++) {
    const int p = mi * 16 + ((lane >> 4) << 2);
#pragma unroll
    for (int nj = 0; nj < 2; nj++) {
      const int n = wn + nj * 16 + (lane & 15);
#pragma unroll
      for (int v = 0; v < 4; v++)
        stp[(size_t)(p + v) * NST + n] = f2bu(accS[mi][nj][v]);
    }
  }
}

// ---------------- inter-chunk state scan (st bf16 -> pv bf16) ---------------
__global__ void k_scan(const unsigned short* __restrict__ st,
                       const float* __restrict__ dac,
                       unsigned short* __restrict__ pv) {
  const int h = blockIdx.x, b = blockIdx.y;
  const int tid = threadIdx.x;
  float P[32];
#pragma unroll
  for (int j = 0; j < 32; j++) P[j] = 0.f;
  for (int c = 0; c < NCH; c++) {
    const size_t base = ((size_t)((b * NCH + c) * NH + h)) * (HD * NST);
#pragma unroll
    for (int j = 0; j < 32; j++) pv[base + tid + 256 * j] = f2bu(P[j]);
    const float d = __expf(dac[((size_t)b * LQ + c * CHK + 255) * NH + h]);
#pragma unroll
    for (int j = 0; j < 32; j++) P[j] = P[j] * d + b2f(st[base + tid + 256 * j]);
  }
}

// -------- fused Y = Y_diag + Y_off + D*x per (b,c,h), single y write --------
__global__ __launch_bounds__(256) void k_y(
    const unsigned short* __restrict__ xbc, const float* __restrict__ dtv,
    const float* __restrict__ dac, const float* __restrict__ cbuf,
    const unsigned short* __restrict__ pv, const float* __restrict__ Dp,
    float* __restrict__ y) {
  const int h = blockIdx.x, c = blockIdx.y, b = blockIdx.z;
  const int cs = c * CHK;
  __shared__ unsigned short lXt[64][136];
  __shared__ unsigned short lS[256][40];
  __shared__ float lda[256];
  __shared__ float lesE[256];
  const int tid = threadIdx.x, lane = tid & 63, w = tid >> 6;
  lda[tid] = dac[((size_t)b * LQ + cs + tid) * NH + h];
  __syncthreads();
  lesE[tid] = __expf(lda[tid | 31] - lda[tid]);
  const float da_t = lda[tid];
  const float* cbp = cbuf + ((size_t)(b * NCH + c)) * (CHK * CHK);
  f32x4 accY[4][4] = {};
  const int sl = tid & 127, sub = tid >> 7;
  // ---- diagonal part: s in [0,256)
  for (int half = 0; half < 2; half++) {
    {
      const int s = half * 128 + sl;
      const size_t row = (size_t)b * LQ + cs + s;
      const unsigned short* xrow = xbc + row * CONVD;
      const float dts = dtv[row * NH + h];
#pragma unroll
      for (int g = 0; g < 4; g++) {
        short8 xv = *reinterpret_cast<const short8*>(xrow + h * HD + sub * 32 + g * 8);
#pragma unroll
        for (int u = 0; u < 8; u++)
          lXt[sub * 32 + g * 8 + u][sl] = f2bu(b2f((unsigned short)xv[u]) * dts);
      }
    }
    __syncthreads();
    for (int sb4 = 0; sb4 < 4; sb4++) {
      const int sb = half * 4 + sb4;
      {
        const int t = tid;
        const int tb = t >> 5;
        if (tb > sb) {
          const float et = __expf(da_t - lda[sb * 32 + 31]);
          const f32x4* cr = reinterpret_cast<const f32x4*>(cbp + (size_t)t * CHK + sb * 32);
          f32x4 vv[8];
#pragma unroll
          for (int j4 = 0; j4 < 8; j4++) vv[j4] = cr[j4];
#pragma unroll
          for (int g = 0; g < 4; g++) {
            short8 pk;
#pragma unroll
            for (int e = 0; e < 8; e++) {
              const int j = g * 8 + e;
              pk[e] = (short)f2bu(vv[j >> 2][j & 3] * et * lesE[sb * 32 + j]);
            }
            *reinterpret_cast<short8*>(&lS[t][g * 8]) = pk;
          }
        } else if (tb == sb) {
          const f32x4* cr = reinterpret_cast<const f32x4*>(cbp + (size_t)t * CHK + sb * 32);
          f32x4 vv[8];
#pragma unroll
          for (int j4 = 0; j4 < 8; j4++) vv[j4] = cr[j4];
          const int tl = t & 31;
#pragma unroll
          for (int g = 0; g < 4; g++) {
            short8 pk;
#pragma unroll
            for (int e = 0; e < 8; e++) {
              const int j = g * 8 + e;
              float val = (j <= tl)
                  ? vv[j >> 2][j & 3] * __expf(da_t - lda[sb * 32 + j]) : 0.f;
              pk[e] = (short)f2bu(val);
            }
            *reinterpret_cast<short8*>(&lS[t][g * 8]) = pk;
          }
        } else {
          short8 z = {};
#pragma unroll
          for (int g = 0; g < 4; g++)
            *reinterpret_cast<short8*>(&lS[tid][g * 8]) = z;
        }
      }
      __syncthreads();
      short8 sf[4], xf[4];
      const int ko = ((lane >> 4) << 3);
      const int so = sb4 * 32 + ko;
#pragma unroll
      for (int i = 0; i < 4; i++) {
        sf[i] = *reinterpret_cast<const short8*>(&lS[w * 64 + i * 16 + (lane & 15)][ko]);
        xf[i] = *reinterpret_cast<const short8*>(&lXt[i * 16 + (lane & 15)][so]);
      }
#pragma unroll
      for (int mi = 0; mi < 4; mi++)
#pragma unroll
        for (int ni = 0; ni < 4; ni++)
          accY[mi][ni] = mfma16(sf[mi], xf[ni], accY[mi][ni]);
      __syncthreads();
    }
  }
  // ---- off part: 4 virtual s-blocks over n in [0,128)
  {
    const unsigned short* pr =
        pv + ((size_t)((b * NCH + c) * NH + h)) * (HD * NST);
    const int p = tid >> 2, qtr = tid & 3;
#pragma unroll
    for (int g = 0; g < 4; g++)
      *reinterpret_cast<short8*>(&lXt[p][qtr * 32 + g * 8]) =
          *reinterpret_cast<const short8*>(pr + (size_t)p * NST + qtr * 32 + g * 8);
  }
  __syncthreads();
  const float et_self = __expf(da_t);  // da_t <= 0, safe
  const unsigned short* crow =
      xbc + ((size_t)b * LQ + cs + tid) * CONVD + DIN + NST;
  for (int sb4 = 0; sb4 < 4; sb4++) {
    {
#pragma unroll
      for (int g = 0; g < 4; g++) {
        short8 cv = *reinterpret_cast<const short8*>(crow + sb4 * 32 + g * 8);
        short8 pk;
#pragma unroll
        for (int e = 0; e < 8; e++)
          pk[e] = (short)f2bu(b2f((unsigned short)cv[e]) * et_self);
        *reinterpret_cast<short8*>(&lS[tid][g * 8]) = pk;
      }
    }
    __syncthreads();
    short8 sf[4], xf[4];
    const int ko = ((lane >> 4) << 3);
    const int so = sb4 * 32 + ko;
#pragma unroll
    for (int i = 0; i < 4; i++) {
      sf[i] = *reinterpret_cast<const short8*>(&lS[w * 64 + i * 16 + (lane & 15)][ko]);
      xf[i] = *reinterpret_cast<const short8*>(&lXt[i * 16 + (lane & 15)][so]);
    }
#pragma unroll
    for (int mi = 0; mi < 4; mi++)
#pragma unroll
      for (int ni = 0; ni < 4; ni++)
        accY[mi][ni] = mfma16(sf[mi], xf[ni], accY[mi][ni]);
    __syncthreads();
  }
  // ---- epilogue: y = accY + D*x (single write)
  const float Dh = Dp[h];
#pragma unroll
  for (int mi = 0; mi < 4; mi++) {
    const int t = w * 64 + mi * 16 + ((lane >> 4) << 2);
#pragma unroll
    for (int ni = 0; ni < 4; ni++) {
      const int p = ni * 16 + (lane & 15);
#pragma unroll
      for (int v = 0; v < 4; v++) {
        const size_t row = (size_t)b * LQ + cs + t + v;
        const float xval = b2f(xbc[row * CONVD + h * HD + p]);
        y[row * DIN + h * HD + p] = accY[mi][ni][v] + Dh * xval;
      }
    }
  }
}

// ---------------- gate*silu + RMSNorm -> bf16 (vectorized) ------------------
__global__ __launch_bounds__(256) void k_gatenorm(
    const float* __restrict__ y, const unsigned short* __restrict__ gateb,
    const float* __restrict__ nw, unsigned short* __restrict__ hgb) {
  const int r = blockIdx.x;
  const int tid = threadIdx.x;
  const int d0 = tid * 16;
  const float* yr = y + (size_t)r * DIN + d0;
  const unsigned short* gr = gateb + (size_t)r * DIN + d0;
  f32x4 yv[4];
  short8 gv[2];
#pragma unroll
  for (int q = 0; q < 4; q++) yv[q] = reinterpret_cast<const f32x4*>(yr)[q];
#pragma unroll
  for (int q = 0; q < 2; q++) gv[q] = reinterpret_cast<const short8*>(gr)[q];
  float hg[16];
  float ss = 0.f;
#pragma unroll
  for (int j = 0; j < 16; j++) {
    const float g = b2f((unsigned short)gv[j >> 3][j & 7]);
    const float v = yv[j >> 2][j & 3] * (g / (1.f + __expf(-g)));
    hg[j] = v;
    ss += v * v;
  }
#pragma unroll
  for (int o = 32; o > 0; o >>= 1) ss += __shfl_down(ss, o);
  __shared__ float red[4];
  if ((tid & 63) == 0) red[tid >> 6] = ss;
  __syncthreads();
  const float tot = red[0] + red[1] + red[2] + red[3];
  const float scale = rsqrtf(tot / (float)DIN + 1e-5f);
  const float* nr = nw + d0;
  short8 o0, o1;
#pragma unroll
  for (int j = 0; j < 16; j++) {
    const unsigned short ov = f2bu(hg[j] * scale * nr[j]);
    if (j < 8) o0[j] = (short)ov;
    else o1[j - 8] = (short)ov;
  }
  unsigned short* hp = hgb + (size_t)r * DIN + d0;
  *reinterpret_cast<short8*>(hp) = o0;
  *reinterpret_cast<short8*>(hp + 8) = o1;
}

extern "C" void kernel_launch(void* const* d_in, const int* in_sizes, int n_in,
                              void* d_out, int out_size, void* d_ws, size_t ws_size,
                              hipStream_t stream) {
  const float* hidden = (const float*)d_in[0];
  const float* w1 = (const float*)d_in[1];
  const float* cw = (const float*)d_in[2];
  const float* cb = (const float*)d_in[3];
  const float* dtb = (const float*)d_in[4];
  const float* alog = (const float*)d_in[5];
  const float* Dp = (const float*)d_in[6];
  const float* nw = (const float*)d_in[7];
  const float* w2 = (const float*)d_in[8];
  float* out = (float*)d_out;
  char* ws = (char*)d_ws;

  // Lifetime-aliased layout. W2B has a DEDICATED region (written S1, read S5).
  const size_t OFF_GATEB = 0;            // bf16 4096x4096   S1-S4
  const size_t OFF_XBC = 33554432;       // bf16 4096x4352   S2-S3
  const size_t OFF_DTV = 104857600;      // f32 4096x64      S2-S3
  const size_t OFF_DAC = 105906176;      // f32 4096x64      S2-S3
  const size_t OFF_CB = 106954752;       // f32 16x256x256   S3
  const size_t OFF_Y = 111149056;        // f32 4096x4096    S3-S4
  const size_t OFF_ST = 178257920;       // bf16 1024x64x128 S3
  const size_t OFF_PV = 211812352;       // bf16 1024x64x128 S3
  const size_t OFF_PROJX = 111149056;    // f32 4096x4416    S1-S2 (aliases Y head)
  const size_t OFF_HB = 183500800;       // bf16 4096x2048   S1 (aliases ST tail)
  const size_t OFF_W1B = 200278016;      // bf16 8704x2048   S1 (aliases PV)
  const size_t OFF_W2B = 245366784;      // bf16 2048x4096   S1-S5 DEDICATED
  const size_t OFF_HGB = 33554432;       // bf16 4096x4096   S4-S5 (aliases XBC)
  const size_t NEED = 262144000;
  if (ws_size < NEED) {
    fprintf(stderr, "WS TOO SMALL: %zu < %zu\n", ws_size, NEED);
    return;
  }
  unsigned short* gateb = (unsigned short*)(ws + OFF_GATEB);
  unsigned short* xbc = (unsigned short*)(ws + OFF_XBC);
  float* dtv = (float*)(ws + OFF_DTV);
  float* dac = (float*)(ws + OFF_DAC);
  float* cbuf = (float*)(ws + OFF_CB);
  float* y = (float*)(ws + OFF_Y);
  unsigned short* st = (unsigned short*)(ws + OFF_ST);
  unsigned short* pv = (unsigned short*)(ws + OFF_PV);
  float* projx = (float*)(ws + OFF_PROJX);
  unsigned short* hb = (unsigned short*)(ws + OFF_HB);
  unsigned short* w1b = (unsigned short*)(ws + OFF_W1B);
  unsigned short* w2b = (unsigned short*)(ws + OFF_W2B);
  unsigned short* hgb = (unsigned short*)(ws + OFF_HGB);

  // S1: fused vectorized casts, then GEMM1
  k_cast3<<<4096, 256, 0, stream>>>(hidden, hb, (long)BL * DMODEL,
                                    w1, w1b, (long)PROJD * DMODEL,
                                    (long)PROJ_PAD2 * DMODEL,
                                    w2, w2b, (long)DMODEL * DIN);
  k_gemm256<true><<<dim3(PROJ_PAD2 / 256, BL / 256), 512, 0, stream>>>(
      hb, w1b, nullptr, gateb, projx, PROJD, DMODEL);
  // S2
  k_conv_silu<<<dim3(17, BL), 256, 0, stream>>>(projx, cw, cb, xbc);
  k_dt<<<16, 512, 0, stream>>>(projx, dtb, alog, dtv, dac);
  // S3
  k_cb<<<dim3(4, 16), 256, 0, stream>>>(xbc, cbuf);
  k_states<<<dim3(NH, NCH, BB), 256, 0, stream>>>(xbc, dtv, dac, st);
  k_scan<<<dim3(NH, BB), 256, 0, stream>>>(st, dac, pv);
  k_y<<<dim3(NH, NCH, BB), 256, 0, stream>>>(xbc, dtv, dac, cbuf, pv, Dp, y);
  // S4
  k_gatenorm<<<BL, 256, 0, stream>>>(y, gateb, nw, hgb);
  // S5
  k_gemm_bt<<<dim3(DMODEL / 128, BL / 128), 256, 0, stream>>>(
      hgb, w2b, out, DMODEL, DIN);
}